// Round 13
// baseline (165.898 us; speedup 1.0000x reference)
//
#include <hip/hip_runtime.h>
#include <stdint.h>

typedef __bf16 bf16x8 __attribute__((ext_vector_type(8)));
typedef float  f32x4  __attribute__((ext_vector_type(4)));
typedef unsigned short u16;

#define AS1 __attribute__((address_space(1)))
#define AS3 __attribute__((address_space(3)))
#define G2L(gp, lp) __builtin_amdgcn_global_load_lds( \
    (const AS1 unsigned int*)(uintptr_t)(gp), \
    (AS3 unsigned int*)(uintptr_t)(lp), 16, 0, 0)

static __device__ __forceinline__ u16 f32_to_bf16(float f) {
    unsigned u = __float_as_uint(f);
    u += 0x7fffu + ((u >> 16) & 1u);
    return (u16)(u >> 16);
}

// bf16 pair pack: lo -> bits[15:0], hi -> bits[31:16]
static __device__ __forceinline__ unsigned pack_bf16(float lo, float hi) {
    return (unsigned)f32_to_bf16(lo) | ((unsigned)f32_to_bf16(hi) << 16);
}

static __device__ __forceinline__ float fast_exp2(float x) {
    return __builtin_amdgcn_exp2f(x);
}

static __device__ __forceinline__ f32x4 mfma16(bf16x8 a, bf16x8 b, f32x4 c) {
    return __builtin_amdgcn_mfma_f32_16x16x32_bf16(a, b, c, 0, 0, 0);
}

// ---------------- fused fp32 -> bf16 convert for x, W_qkv, W_out ----------------
__global__ void cvt3_k(const float* __restrict__ a, const float* __restrict__ b,
                       const float* __restrict__ c, u16* __restrict__ out) {
    const int i = blockIdx.x * blockDim.x + threadIdx.x;   // vec4 index
    const float* src; int off;
    if (i < 1572864)      { src = a; off = 0; }
    else if (i < 2015232) { src = b; off = 1572864; }
    else                  { src = c; off = 2015232; }
    const float4 v = reinterpret_cast<const float4*>(src)[i - off];
    reinterpret_cast<uint2*>(out)[i] = make_uint2(pack_bf16(v.x, v.y), pack_bf16(v.z, v.w));
}

// ---------------- bf16 GEMM v4: direct-A + staged-B ----------------
// C[M,N] = A[M,K] @ B[N,K]^T + bias. 128x128 tile, BK=64.
// A fragments load straight global->VGPR (K-major, per-lane 16B; L1 line reuse
// across kk). B staged in LDS, 2-phase G2L dbuf (full 128B-line staging,
// 0-conflict swizzle ch^(row&7)). LDS 32KB -> 3 blocks/CU (12 waves).
// Columns gc < qcols scaled by qsc (pre-folds softmax scale into Q).
template<int OUTF32>
__global__ __launch_bounds__(256, 3) void gemm_bt_k(const u16* __restrict__ A, const u16* __restrict__ B,
                                                    const float* __restrict__ bias, void* __restrict__ Cp,
                                                    int M, int N, int K, int nbx, int qcols, float qsc) {
    __shared__ __align__(16) u16 Bs[2][128 * 64];
    const int id = blockIdx.x;
    const int cpx = gridDim.x >> 3;                       // grid divisible by 8
    const int swz = (id & 7) * cpx + (id >> 3);           // bijective XCD swizzle
    const int bx = swz % nbx, by = swz / nbx;
    const int t = threadIdx.x, w = t >> 6, l = t & 63, lr = l & 15, lg = l >> 4;
    const int wr = w >> 1, wc = w & 1;
    const long rowBase = (long)by * 128;
    const long colBase = (long)bx * 128;

    const f32x4 z = {0.f, 0.f, 0.f, 0.f};
    f32x4 acc[4][4];
    #pragma unroll
    for (int m = 0; m < 4; ++m)
        #pragma unroll
        for (int n = 0; n < 4; ++n) acc[m][n] = z;

    const int kSteps = K >> 6;
    // A base for this wave's rows (row = wr*64 + m*16 + lr)
    const u16* aBase = A + (rowBase + wr * 64 + lr) * (long)K;

    // prologue: stage B tile 0 into buf 0 (4 G2L/thread, full 128B rows)
    #pragma unroll
    for (int i = 0; i < 4; ++i) {
        const int c = i * 256 + t, row = c >> 3, ch = c & 7;
        const int sch = ch ^ (row & 7);
        G2L(B + (colBase + row) * K + sch * 8, &Bs[0][(i * 256 + w * 64) * 8]);
    }
    for (int kt = 0; kt < kSteps; ++kt) {
        const int cur = kt & 1;
        asm volatile("s_waitcnt vmcnt(0)" ::: "memory");   // my B-stage writes landed
        __builtin_amdgcn_sched_barrier(0);
        __builtin_amdgcn_s_barrier();                      // tile kt resident; prev reads done
        __builtin_amdgcn_sched_barrier(0);
        if (kt + 1 < kSteps) {                             // stage B(t+1), hidden under compute
            const int k0 = (kt + 1) << 6;
            #pragma unroll
            for (int i = 0; i < 4; ++i) {
                const int c = i * 256 + t, row = c >> 3, ch = c & 7;
                const int sch = ch ^ (row & 7);
                G2L(B + (colBase + row) * K + k0 + sch * 8, &Bs[cur ^ 1][(i * 256 + w * 64) * 8]);
            }
        }
        __builtin_amdgcn_sched_barrier(0);
        const int k0 = kt << 6;
        #pragma unroll
        for (int kk = 0; kk < 2; ++kk) {
            bf16x8 af[4], bfr[4];
            #pragma unroll
            for (int m = 0; m < 4; ++m)
                af[m] = *reinterpret_cast<const bf16x8*>(aBase + (long)m * 16 * K + k0 + (kk * 4 + lg) * 8);
            #pragma unroll
            for (int n = 0; n < 4; ++n) {
                const int row = wc * 64 + n * 16 + lr;
                bfr[n] = *reinterpret_cast<const bf16x8*>(&Bs[cur][row * 64 + (((kk * 4 + lg) ^ (lr & 7)) << 3)]);
            }
            #pragma unroll
            for (int m = 0; m < 4; ++m)
                #pragma unroll
                for (int n = 0; n < 4; ++n) acc[m][n] = mfma16(af[m], bfr[n], acc[m][n]);
        }
    }
    #pragma unroll
    for (int n = 0; n < 4; ++n) {
        const long gc = colBase + wc * 64 + n * 16 + lr;
        const float bv = bias[gc];
        const float csc = (gc < qcols) ? qsc : 1.0f;
        #pragma unroll
        for (int m = 0; m < 4; ++m) {
            const long gr = rowBase + wr * 64 + m * 16 + lg * 4;
            #pragma unroll
            for (int r = 0; r < 4; ++r) {
                const float v = (acc[m][n][r] + bv) * csc;
                if (OUTF32) reinterpret_cast<float*>(Cp)[(gr + r) * N + gc] = v;
                else        reinterpret_cast<u16*>(Cp)[(gr + r) * N + gc] = f32_to_bf16(v);
            }
        }
    }
}

// ---------------- V transpose with PV k-permutation pi' ----------------
// vt[bh][d][pos p] = V[key = (p>>5)*32 + ((p>>2)&1)*16 + ((p>>3)&3)*4 + (p&3)][d]
__global__ __launch_bounds__(256) void transpose_v_k(const u16* __restrict__ qkv, u16* __restrict__ vt) {
    const int bh = blockIdx.y, b = bh / 12, h = bh % 12;
    const int nt = blockIdx.x;
    __shared__ __align__(16) u16 Ts[64][72];   // [key][d]
    const int t = threadIdx.x;
    const int rr = t >> 2;
    #pragma unroll
    for (int i = 0; i < 2; ++i) {
        const int ch = (t & 3) + i * 4;
        const u16* src = qkv + (long)(b * 1024 + nt * 64 + rr) * 2304 + 1536 + h * 64 + ch * 8;
        *reinterpret_cast<uint4*>(&Ts[rr][ch * 8]) = *reinterpret_cast<const uint4*>(src);
    }
    __syncthreads();
    #pragma unroll
    for (int i = 0; i < 2; ++i) {
        const int ch = (t & 3) + i * 4;   // pos p = ch*8+j
        u16 vals[8];
        #pragma unroll
        for (int j = 0; j < 8; ++j)
            vals[j] = Ts[(ch >> 2) * 32 + (j >> 2) * 16 + (ch & 3) * 4 + (j & 3)][rr];
        u16* dst = vt + (long)(bh * 64 + rr) * 1024 + nt * 64 + ch * 8;
        *reinterpret_cast<uint4*>(dst) = *reinterpret_cast<const uint4*>(vals);
    }
}

// ---------------- flash attention v7: swapped-QK, in-register P, QBLK=128 ----------------
__global__ __launch_bounds__(256, 3) void attn_k(const u16* __restrict__ qkv, const u16* __restrict__ vt,
                                                 u16* __restrict__ outp) {
    const int id = blockIdx.x;
    const int bh = id % 96, qt = id / 96;   // qt in 0..7; same-bh -> same XCD
    const int b = bh / 12, h = bh % 12;
    const int t = threadIdx.x, w = t >> 6, l = t & 63, lr = l & 15, lg = l >> 4;
    __shared__ __align__(16) u16 Ks[2][64 * 64];
    __shared__ __align__(16) u16 Vts[2][64 * 64];   // [d][perm key]

    const u16* kb = qkv + 768 + h * 64;
    const u16* vb = vt + (long)bh * 64 * 1024;

    #pragma unroll
    for (int i = 0; i < 2; ++i) {
        const int c = (i * 4 + w) * 64 + l;
        const int row = c >> 3, sch = (c & 7) ^ (row & 7);
        G2L(kb + (long)(b * 1024 + row) * 2304 + sch * 8, &Ks[0][(i * 4 + w) * 512]);
        G2L(vb + (long)row * 1024 + sch * 8, &Vts[0][(i * 4 + w) * 512]);
    }
    const u16* qb = qkv + (long)(b * 1024 + qt * 128 + w * 32) * 2304 + h * 64;
    bf16x8 aq[2][2];
    #pragma unroll
    for (int qf = 0; qf < 2; ++qf)
        #pragma unroll
        for (int kk = 0; kk < 2; ++kk)
            aq[qf][kk] = *reinterpret_cast<const bf16x8*>(qb + (long)(qf * 16 + lr) * 2304 + (kk * 4 + lg) * 8);

    const f32x4 z = {0.f, 0.f, 0.f, 0.f};
    f32x4 o[2][4];
    f32x4 dacc[2];
    #pragma unroll
    for (int qf = 0; qf < 2; ++qf) {
        #pragma unroll
        for (int n = 0; n < 4; ++n) o[qf][n] = z;
        dacc[qf] = z;
    }
    const unsigned one2 = 0x3F803F80u;
    uint4 onesu = make_uint4(one2, one2, one2, one2);
    const bf16x8 ones = *reinterpret_cast<const bf16x8*>(&onesu);

    #pragma unroll 2
    for (int kt = 0; kt < 16; ++kt) {
        const int cur = kt & 1;
        asm volatile("s_waitcnt vmcnt(0)" ::: "memory");
        __builtin_amdgcn_sched_barrier(0);
        __builtin_amdgcn_s_barrier();
        __builtin_amdgcn_sched_barrier(0);
        if (kt < 15) {
            const int ktn = kt + 1;
            #pragma unroll
            for (int i = 0; i < 2; ++i) {
                const int c = (i * 4 + w) * 64 + l;
                const int row = c >> 3, sch = (c & 7) ^ (row & 7);
                G2L(kb + (long)(b * 1024 + ktn * 64 + row) * 2304 + sch * 8, &Ks[cur ^ 1][(i * 4 + w) * 512]);
                G2L(vb + (long)row * 1024 + ktn * 64 + sch * 8, &Vts[cur ^ 1][(i * 4 + w) * 512]);
            }
        }
        __builtin_amdgcn_sched_barrier(0);
        // S^T = K @ Q^T: s[kc][qf] = S[key=kc*16+lg*4+r][q=qf*16+lr]
        f32x4 s[4][2];
        #pragma unroll
        for (int kc = 0; kc < 4; ++kc)
            #pragma unroll
            for (int qf = 0; qf < 2; ++qf) s[kc][qf] = z;
        #pragma unroll
        for (int kk = 0; kk < 2; ++kk) {
            #pragma unroll
            for (int kc = 0; kc < 4; ++kc) {
                const int row = kc * 16 + lr;
                bf16x8 bk = *reinterpret_cast<const bf16x8*>(&Ks[cur][row * 64 + (((kk * 4 + lg) ^ (lr & 7)) << 3)]);
                s[kc][0] = mfma16(bk, aq[0][kk], s[kc][0]);
                s[kc][1] = mfma16(bk, aq[1][kk], s[kc][1]);
            }
        }
        // softmax-lite in-register: p = exp2(s), pack straight to PV A-operand
        #pragma unroll
        for (int qf = 0; qf < 2; ++qf) {
            float pv[4][4];
            #pragma unroll
            for (int kc = 0; kc < 4; ++kc)
                #pragma unroll
                for (int r = 0; r < 4; ++r)
                    pv[kc][r] = fast_exp2(s[kc][qf][r]);
            uint4 u0, u1;
            u0.x = pack_bf16(pv[0][0], pv[0][1]); u0.y = pack_bf16(pv[0][2], pv[0][3]);
            u0.z = pack_bf16(pv[1][0], pv[1][1]); u0.w = pack_bf16(pv[1][2], pv[1][3]);
            u1.x = pack_bf16(pv[2][0], pv[2][1]); u1.y = pack_bf16(pv[2][2], pv[2][3]);
            u1.z = pack_bf16(pv[3][0], pv[3][1]); u1.w = pack_bf16(pv[3][2], pv[3][3]);
            bf16x8 pa0 = *reinterpret_cast<bf16x8*>(&u0);
            bf16x8 pa1 = *reinterpret_cast<bf16x8*>(&u1);
            dacc[qf] = mfma16(pa0, ones, dacc[qf]);
            dacc[qf] = mfma16(pa1, ones, dacc[qf]);
            #pragma unroll
            for (int kk = 0; kk < 2; ++kk) {
                const bf16x8 pa = kk ? pa1 : pa0;
                const int swzk = ((kk * 4 + lg) ^ (lr & 7)) << 3;
                #pragma unroll
                for (int n = 0; n < 4; ++n) {
                    const int row = n * 16 + lr;
                    bf16x8 vbf = *reinterpret_cast<const bf16x8*>(&Vts[cur][row * 64 + swzk]);
                    o[qf][n] = mfma16(pa, vbf, o[qf][n]);
                }
            }
        }
    }
    #pragma unroll
    for (int qf = 0; qf < 2; ++qf) {
        const int qrow = qt * 128 + w * 32 + qf * 16 + lg * 4;
        #pragma unroll
        for (int r = 0; r < 4; ++r) {
            const float inv = 1.0f / dacc[qf][r];
            #pragma unroll
            for (int n = 0; n < 4; ++n) {
                outp[(long)(b * 1024 + qrow + r) * 768 + h * 64 + n * 16 + lr] =
                    f32_to_bf16(o[qf][n][r] * inv);
            }
        }
    }
}

extern "C" void kernel_launch(void* const* d_in, const int* in_sizes, int n_in,
                              void* d_out, int out_size, void* d_ws, size_t ws_size,
                              hipStream_t stream) {
    (void)in_sizes; (void)n_in; (void)out_size; (void)ws_size;
    const float* x    = (const float*)d_in[0];
    const float* Wqkv = (const float*)d_in[1];
    const float* bqkv = (const float*)d_in[2];
    const float* Wout = (const float*)d_in[3];
    const float* bout = (const float*)d_in[4];

    u16* xb   = (u16*)d_ws;          // 8192*768
    u16* Wqb  = xb  + 6291456;       // 2304*768
    u16* Wob  = Wqb + 1769472;       // 768*768
    u16* qkv  = Wob + 589824;        // 8192*2304
    u16* vtb  = qkv + 18874368;      // 96*64*1024
    u16* attn = vtb + 6291456;       // 8192*768

    const float sc2 = 0.052058773f;  // 768^-0.5 * log2(e)

    cvt3_k<<<8448, 256, 0, stream>>>(x, Wqkv, Wout, xb);

    gemm_bt_k<0><<<1152, 256, 0, stream>>>(xb, Wqb, bqkv, qkv, 8192, 2304, 768, 18, 768, sc2);
    transpose_v_k<<<dim3(16, 96), 256, 0, stream>>>(qkv, vtb);
    attn_k<<<768, 256, 0, stream>>>(qkv, vtb, attn);
    gemm_bt_k<1><<<384, 256, 0, stream>>>(attn, Wob, bout, d_out, 8192, 768, 768, 6, 0, 1.0f);
}

// Round 14
// 154.408 us; speedup vs baseline: 1.0744x; 1.0744x over previous
//
#include <hip/hip_runtime.h>
#include <stdint.h>

typedef __bf16 bf16x8 __attribute__((ext_vector_type(8)));
typedef float  f32x4  __attribute__((ext_vector_type(4)));
typedef unsigned short u16;

#define AS1 __attribute__((address_space(1)))
#define AS3 __attribute__((address_space(3)))
#define G2L(gp, lp) __builtin_amdgcn_global_load_lds( \
    (const AS1 unsigned int*)(uintptr_t)(gp), \
    (AS3 unsigned int*)(uintptr_t)(lp), 16, 0, 0)

static __device__ __forceinline__ u16 f32_to_bf16(float f) {
    unsigned u = __float_as_uint(f);
    u += 0x7fffu + ((u >> 16) & 1u);
    return (u16)(u >> 16);
}

// bf16 pair pack: lo -> bits[15:0], hi -> bits[31:16]
static __device__ __forceinline__ unsigned pack_bf16(float lo, float hi) {
    return (unsigned)f32_to_bf16(lo) | ((unsigned)f32_to_bf16(hi) << 16);
}

static __device__ __forceinline__ float fast_exp2(float x) {
    return __builtin_amdgcn_exp2f(x);
}

static __device__ __forceinline__ f32x4 mfma16(bf16x8 a, bf16x8 b, f32x4 c) {
    return __builtin_amdgcn_mfma_f32_16x16x32_bf16(a, b, c, 0, 0, 0);
}

// ---------------- fused fp32 -> bf16 convert for x, W_qkv, W_out ----------------
__global__ void cvt3_k(const float* __restrict__ a, const float* __restrict__ b,
                       const float* __restrict__ c, u16* __restrict__ out) {
    const int i = blockIdx.x * blockDim.x + threadIdx.x;   // vec4 index
    const float* src; int off;
    if (i < 1572864)      { src = a; off = 0; }
    else if (i < 2015232) { src = b; off = 1572864; }
    else                  { src = c; off = 2015232; }
    const float4 v = reinterpret_cast<const float4*>(src)[i - off];
    reinterpret_cast<uint2*>(out)[i] = make_uint2(pack_bf16(v.x, v.y), pack_bf16(v.z, v.w));
}

// ---------------- bf16 GEMM v5: reg-prefetched direct-A + LDS-staged B ----------------
// C[M,N] = A[M,K] @ B[N,K]^T + bias. 128x128 tile, BK=64, 4 waves (2x2).
// B: LDS dbuf, 2-phase G2L (R10-proven schedule + 0-conflict swizzle).
// A: direct global->VGPR, double-buffered in registers one K-step ahead
// (issued right after the barrier -> full compute phase hides L2 latency).
// Static reg indexing via even/odd body unroll (no scratch).
// LDS-port traffic halves vs R10 (8 instead of 16 ds_read_b128/wave/step).
template<int OUTF32>
__global__ __launch_bounds__(256, 2) void gemm_bt_k(const u16* __restrict__ A, const u16* __restrict__ B,
                                                    const float* __restrict__ bias, void* __restrict__ Cp,
                                                    int M, int N, int K, int nbx, int qcols, float qsc) {
    __shared__ __align__(16) u16 Bs[2][128 * 64];
    const int id = blockIdx.x;
    const int cpx = gridDim.x >> 3;                       // grid divisible by 8
    const int swz = (id & 7) * cpx + (id >> 3);           // bijective XCD swizzle
    const int bx = swz % nbx, by = swz / nbx;
    const int t = threadIdx.x, w = t >> 6, l = t & 63, lr = l & 15, lg = l >> 4;
    const int wr = w >> 1, wc = w & 1;
    const long rowBase = (long)by * 128;
    const long colBase = (long)bx * 128;

    const f32x4 z = {0.f, 0.f, 0.f, 0.f};
    f32x4 acc[4][4];
    #pragma unroll
    for (int m = 0; m < 4; ++m)
        #pragma unroll
        for (int n = 0; n < 4; ++n) acc[m][n] = z;

    const int kSteps = K >> 6;
    const u16* aBase = A + (rowBase + wr * 64 + lr) * (long)K;

    // stage B tile kt into buffer bi (4 G2L/thread, full 128B rows, swizzled src)
    #define STAGE_B(kt, bi) do {                                                    \
        const int k0_ = (kt) << 6;                                                  \
        _Pragma("unroll")                                                           \
        for (int i_ = 0; i_ < 4; ++i_) {                                            \
            const int c_ = i_ * 256 + t, row_ = c_ >> 3, ch_ = c_ & 7;              \
            const int sch_ = ch_ ^ (row_ & 7);                                      \
            G2L(B + (colBase + row_) * K + k0_ + sch_ * 8, &Bs[bi][(i_ * 256 + w * 64) * 8]); \
        }                                                                           \
    } while (0)

    // load A fragments for K-tile kt into DST (8 b128 global loads)
    #define LOAD_A(DST, kt) do {                                                    \
        const int k0_ = (kt) << 6;                                                  \
        _Pragma("unroll")                                                           \
        for (int kk_ = 0; kk_ < 2; ++kk_)                                           \
            _Pragma("unroll")                                                       \
            for (int m_ = 0; m_ < 4; ++m_)                                          \
                DST[kk_ * 4 + m_] = *reinterpret_cast<const bf16x8*>(               \
                    aBase + (long)m_ * 16 * K + k0_ + (kk_ * 4 + lg) * 8);          \
    } while (0)

    // one K-step body: consume CUR (tile kt), prefetch NXT (tile kt+1)
    #define BODY(kt, CUR, NXT) do {                                                 \
        const int cur_ = (kt) & 1;                                                  \
        asm volatile("s_waitcnt vmcnt(0)" ::: "memory");                            \
        __builtin_amdgcn_sched_barrier(0);                                          \
        __builtin_amdgcn_s_barrier();                                               \
        __builtin_amdgcn_sched_barrier(0);                                          \
        if ((kt) + 1 < kSteps) {                                                    \
            STAGE_B((kt) + 1, cur_ ^ 1);                                            \
            LOAD_A(NXT, (kt) + 1);                                                  \
        }                                                                           \
        __builtin_amdgcn_sched_barrier(0);                                          \
        _Pragma("unroll")                                                           \
        for (int kk_ = 0; kk_ < 2; ++kk_) {                                         \
            bf16x8 bfr_[4];                                                         \
            _Pragma("unroll")                                                       \
            for (int n_ = 0; n_ < 4; ++n_) {                                        \
                const int row_ = wc * 64 + n_ * 16 + lr;                            \
                bfr_[n_] = *reinterpret_cast<const bf16x8*>(                        \
                    &Bs[cur_][row_ * 64 + (((kk_ * 4 + lg) ^ (lr & 7)) << 3)]);     \
            }                                                                       \
            _Pragma("unroll")                                                       \
            for (int m_ = 0; m_ < 4; ++m_)                                          \
                _Pragma("unroll")                                                   \
                for (int n_ = 0; n_ < 4; ++n_)                                      \
                    acc[m_][n_] = mfma16(CUR[kk_ * 4 + m_], bfr_[n_], acc[m_][n_]); \
        }                                                                           \
    } while (0)

    bf16x8 afA[8], afB[8];
    STAGE_B(0, 0);
    LOAD_A(afA, 0);
    const int kPairs = kSteps >> 1;   // kSteps is even (12 for K=768)
    for (int kp = 0; kp < kPairs; ++kp) {
        BODY(2 * kp, afA, afB);
        BODY(2 * kp + 1, afB, afA);
    }
    #undef STAGE_B
    #undef LOAD_A
    #undef BODY

    #pragma unroll
    for (int n = 0; n < 4; ++n) {
        const long gc = colBase + wc * 64 + n * 16 + lr;
        const float bv = bias[gc];
        const float csc = (gc < qcols) ? qsc : 1.0f;
        #pragma unroll
        for (int m = 0; m < 4; ++m) {
            const long gr = rowBase + wr * 64 + m * 16 + lg * 4;
            #pragma unroll
            for (int r = 0; r < 4; ++r) {
                const float v = (acc[m][n][r] + bv) * csc;
                if (OUTF32) reinterpret_cast<float*>(Cp)[(gr + r) * N + gc] = v;
                else        reinterpret_cast<u16*>(Cp)[(gr + r) * N + gc] = f32_to_bf16(v);
            }
        }
    }
}

// ---------------- V transpose with PV k-permutation pi' ----------------
// vt[bh][d][pos p] = V[key = (p>>5)*32 + ((p>>2)&1)*16 + ((p>>3)&3)*4 + (p&3)][d]
__global__ __launch_bounds__(256) void transpose_v_k(const u16* __restrict__ qkv, u16* __restrict__ vt) {
    const int bh = blockIdx.y, b = bh / 12, h = bh % 12;
    const int nt = blockIdx.x;
    __shared__ __align__(16) u16 Ts[64][72];   // [key][d]
    const int t = threadIdx.x;
    const int rr = t >> 2;
    #pragma unroll
    for (int i = 0; i < 2; ++i) {
        const int ch = (t & 3) + i * 4;
        const u16* src = qkv + (long)(b * 1024 + nt * 64 + rr) * 2304 + 1536 + h * 64 + ch * 8;
        *reinterpret_cast<uint4*>(&Ts[rr][ch * 8]) = *reinterpret_cast<const uint4*>(src);
    }
    __syncthreads();
    #pragma unroll
    for (int i = 0; i < 2; ++i) {
        const int ch = (t & 3) + i * 4;   // pos p = ch*8+j
        u16 vals[8];
        #pragma unroll
        for (int j = 0; j < 8; ++j)
            vals[j] = Ts[(ch >> 2) * 32 + (j >> 2) * 16 + (ch & 3) * 4 + (j & 3)][rr];
        u16* dst = vt + (long)(bh * 64 + rr) * 1024 + nt * 64 + ch * 8;
        *reinterpret_cast<uint4*>(dst) = *reinterpret_cast<const uint4*>(vals);
    }
}

// ---------------- flash attention v7: swapped-QK, in-register P, QBLK=128 ----------------
__global__ __launch_bounds__(256, 3) void attn_k(const u16* __restrict__ qkv, const u16* __restrict__ vt,
                                                 u16* __restrict__ outp) {
    const int id = blockIdx.x;
    const int bh = id % 96, qt = id / 96;   // qt in 0..7; same-bh -> same XCD
    const int b = bh / 12, h = bh % 12;
    const int t = threadIdx.x, w = t >> 6, l = t & 63, lr = l & 15, lg = l >> 4;
    __shared__ __align__(16) u16 Ks[2][64 * 64];
    __shared__ __align__(16) u16 Vts[2][64 * 64];   // [d][perm key]

    const u16* kb = qkv + 768 + h * 64;
    const u16* vb = vt + (long)bh * 64 * 1024;

    #pragma unroll
    for (int i = 0; i < 2; ++i) {
        const int c = (i * 4 + w) * 64 + l;
        const int row = c >> 3, sch = (c & 7) ^ (row & 7);
        G2L(kb + (long)(b * 1024 + row) * 2304 + sch * 8, &Ks[0][(i * 4 + w) * 512]);
        G2L(vb + (long)row * 1024 + sch * 8, &Vts[0][(i * 4 + w) * 512]);
    }
    const u16* qb = qkv + (long)(b * 1024 + qt * 128 + w * 32) * 2304 + h * 64;
    bf16x8 aq[2][2];
    #pragma unroll
    for (int qf = 0; qf < 2; ++qf)
        #pragma unroll
        for (int kk = 0; kk < 2; ++kk)
            aq[qf][kk] = *reinterpret_cast<const bf16x8*>(qb + (long)(qf * 16 + lr) * 2304 + (kk * 4 + lg) * 8);

    const f32x4 z = {0.f, 0.f, 0.f, 0.f};
    f32x4 o[2][4];
    f32x4 dacc[2];
    #pragma unroll
    for (int qf = 0; qf < 2; ++qf) {
        #pragma unroll
        for (int n = 0; n < 4; ++n) o[qf][n] = z;
        dacc[qf] = z;
    }
    const unsigned one2 = 0x3F803F80u;
    uint4 onesu = make_uint4(one2, one2, one2, one2);
    const bf16x8 ones = *reinterpret_cast<const bf16x8*>(&onesu);

    #pragma unroll 2
    for (int kt = 0; kt < 16; ++kt) {
        const int cur = kt & 1;
        asm volatile("s_waitcnt vmcnt(0)" ::: "memory");
        __builtin_amdgcn_sched_barrier(0);
        __builtin_amdgcn_s_barrier();
        __builtin_amdgcn_sched_barrier(0);
        if (kt < 15) {
            const int ktn = kt + 1;
            #pragma unroll
            for (int i = 0; i < 2; ++i) {
                const int c = (i * 4 + w) * 64 + l;
                const int row = c >> 3, sch = (c & 7) ^ (row & 7);
                G2L(kb + (long)(b * 1024 + ktn * 64 + row) * 2304 + sch * 8, &Ks[cur ^ 1][(i * 4 + w) * 512]);
                G2L(vb + (long)row * 1024 + ktn * 64 + sch * 8, &Vts[cur ^ 1][(i * 4 + w) * 512]);
            }
        }
        __builtin_amdgcn_sched_barrier(0);
        // S^T = K @ Q^T: s[kc][qf] = S[key=kc*16+lg*4+r][q=qf*16+lr]
        f32x4 s[4][2];
        #pragma unroll
        for (int kc = 0; kc < 4; ++kc)
            #pragma unroll
            for (int qf = 0; qf < 2; ++qf) s[kc][qf] = z;
        #pragma unroll
        for (int kk = 0; kk < 2; ++kk) {
            #pragma unroll
            for (int kc = 0; kc < 4; ++kc) {
                const int row = kc * 16 + lr;
                bf16x8 bk = *reinterpret_cast<const bf16x8*>(&Ks[cur][row * 64 + (((kk * 4 + lg) ^ (lr & 7)) << 3)]);
                s[kc][0] = mfma16(bk, aq[0][kk], s[kc][0]);
                s[kc][1] = mfma16(bk, aq[1][kk], s[kc][1]);
            }
        }
        // softmax-lite in-register: p = exp2(s), pack straight to PV A-operand
        #pragma unroll
        for (int qf = 0; qf < 2; ++qf) {
            float pv[4][4];
            #pragma unroll
            for (int kc = 0; kc < 4; ++kc)
                #pragma unroll
                for (int r = 0; r < 4; ++r)
                    pv[kc][r] = fast_exp2(s[kc][qf][r]);
            uint4 u0, u1;
            u0.x = pack_bf16(pv[0][0], pv[0][1]); u0.y = pack_bf16(pv[0][2], pv[0][3]);
            u0.z = pack_bf16(pv[1][0], pv[1][1]); u0.w = pack_bf16(pv[1][2], pv[1][3]);
            u1.x = pack_bf16(pv[2][0], pv[2][1]); u1.y = pack_bf16(pv[2][2], pv[2][3]);
            u1.z = pack_bf16(pv[3][0], pv[3][1]); u1.w = pack_bf16(pv[3][2], pv[3][3]);
            bf16x8 pa0 = *reinterpret_cast<bf16x8*>(&u0);
            bf16x8 pa1 = *reinterpret_cast<bf16x8*>(&u1);
            dacc[qf] = mfma16(pa0, ones, dacc[qf]);
            dacc[qf] = mfma16(pa1, ones, dacc[qf]);
            #pragma unroll
            for (int kk = 0; kk < 2; ++kk) {
                const bf16x8 pa = kk ? pa1 : pa0;
                const int swzk = ((kk * 4 + lg) ^ (lr & 7)) << 3;
                #pragma unroll
                for (int n = 0; n < 4; ++n) {
                    const int row = n * 16 + lr;
                    bf16x8 vbf = *reinterpret_cast<const bf16x8*>(&Vts[cur][row * 64 + swzk]);
                    o[qf][n] = mfma16(pa, vbf, o[qf][n]);
                }
            }
        }
    }
    #pragma unroll
    for (int qf = 0; qf < 2; ++qf) {
        const int qrow = qt * 128 + w * 32 + qf * 16 + lg * 4;
        #pragma unroll
        for (int r = 0; r < 4; ++r) {
            const float inv = 1.0f / dacc[qf][r];
            #pragma unroll
            for (int n = 0; n < 4; ++n) {
                outp[(long)(b * 1024 + qrow + r) * 768 + h * 64 + n * 16 + lr] =
                    f32_to_bf16(o[qf][n][r] * inv);
            }
        }
    }
}

extern "C" void kernel_launch(void* const* d_in, const int* in_sizes, int n_in,
                              void* d_out, int out_size, void* d_ws, size_t ws_size,
                              hipStream_t stream) {
    (void)in_sizes; (void)n_in; (void)out_size; (void)ws_size;
    const float* x    = (const float*)d_in[0];
    const float* Wqkv = (const float*)d_in[1];
    const float* bqkv = (const float*)d_in[2];
    const float* Wout = (const float*)d_in[3];
    const float* bout = (const float*)d_in[4];

    u16* xb   = (u16*)d_ws;          // 8192*768
    u16* Wqb  = xb  + 6291456;       // 2304*768
    u16* Wob  = Wqb + 1769472;       // 768*768
    u16* qkv  = Wob + 589824;        // 8192*2304
    u16* vtb  = qkv + 18874368;      // 96*64*1024
    u16* attn = vtb + 6291456;       // 8192*768

    const float sc2 = 0.052058773f;  // 768^-0.5 * log2(e)

    cvt3_k<<<8448, 256, 0, stream>>>(x, Wqkv, Wout, xb);

    gemm_bt_k<0><<<1152, 256, 0, stream>>>(xb, Wqb, bqkv, qkv, 8192, 2304, 768, 18, 768, sc2);
    transpose_v_k<<<dim3(16, 96), 256, 0, stream>>>(qkv, vtb);
    attn_k<<<768, 256, 0, stream>>>(qkv, vtb, attn);
    gemm_bt_k<1><<<384, 256, 0, stream>>>(attn, Wob, bout, d_out, 8192, 768, 768, 6, 0, 1.0f);
}

// Round 15
// 133.035 us; speedup vs baseline: 1.2470x; 1.1607x over previous
//
#include <hip/hip_runtime.h>
#include <stdint.h>

typedef __bf16 bf16x8 __attribute__((ext_vector_type(8)));
typedef float  f32x4  __attribute__((ext_vector_type(4)));
typedef unsigned short u16;

#define AS1 __attribute__((address_space(1)))
#define AS3 __attribute__((address_space(3)))
#define G2L(gp, lp) __builtin_amdgcn_global_load_lds( \
    (const AS1 unsigned int*)(uintptr_t)(gp), \
    (AS3 unsigned int*)(uintptr_t)(lp), 16, 0, 0)

static __device__ __forceinline__ u16 f32_to_bf16(float f) {
    unsigned u = __float_as_uint(f);
    u += 0x7fffu + ((u >> 16) & 1u);
    return (u16)(u >> 16);
}

static __device__ __forceinline__ unsigned pack_bf16(float lo, float hi) {
    return (unsigned)f32_to_bf16(lo) | ((unsigned)f32_to_bf16(hi) << 16);
}

static __device__ __forceinline__ float fast_exp2(float x) {
    return __builtin_amdgcn_exp2f(x);
}

static __device__ __forceinline__ f32x4 mfma16(bf16x8 a, bf16x8 b, f32x4 c) {
    return __builtin_amdgcn_mfma_f32_16x16x32_bf16(a, b, c, 0, 0, 0);
}

// ---------------- fused fp32 -> bf16 convert for x, W_qkv, W_out ----------------
__global__ void cvt3_k(const float* __restrict__ a, const float* __restrict__ b,
                       const float* __restrict__ c, u16* __restrict__ out) {
    const int i = blockIdx.x * blockDim.x + threadIdx.x;   // vec4 index
    const float* src; int off;
    if (i < 1572864)      { src = a; off = 0; }
    else if (i < 2015232) { src = b; off = 1572864; }
    else                  { src = c; off = 2015232; }
    const float4 v = reinterpret_cast<const float4*>(src)[i - off];
    reinterpret_cast<uint2*>(out)[i] = make_uint2(pack_bf16(v.x, v.y), pack_bf16(v.z, v.w));
}

// ---------------- bf16 GEMM v6: 256x256 8-phase counted-vmcnt (T2+T3+T4+T5) ----------------
// C[M,N] = A[M,K] @ B[N,K]^T + bias. 512 threads = 8 waves (2M x 4N), BK=64.
// Per wave: 128x64 output = 8x4 frags. LDS 128KB dynamic: per matrix 2buf x 2half
// x [128][64] u16. 4 phases per K-tile: {stage 1 half-tile || ds-read frags ->
// barrier -> lgkmcnt(0) -> setprio(1) 16 MFMA setprio(0)}. Counted vmcnt(4) at
// tile top (never 0 mid-loop): A staged 1 tile ahead (ph0/ph1), B staged 2 tiles
// ahead (ph2/ph3) -> the wait leaves next tile's B in flight. Swizzle ch^(row&7)
// (proven 0-conflict). Columns gc < qcols scaled by qsc.
template<int OUTF32>
__global__ __launch_bounds__(512, 2) void gemm256_k(const u16* __restrict__ A, const u16* __restrict__ B,
                                                    const float* __restrict__ bias, void* __restrict__ Cp,
                                                    int M, int N, int K, int nbx, int qcols, float qsc) {
    extern __shared__ __align__(16) u16 lds[];
    const int id = blockIdx.x;
    const int cpx = gridDim.x >> 3;                       // grid divisible by 8
    const int swz = (id & 7) * cpx + (id >> 3);           // bijective XCD swizzle
    const int bx = swz % nbx, by = swz / nbx;
    const int t = threadIdx.x;                            // 0..511
    const int w = t >> 6, l = t & 63, lr = l & 15, lg = l >> 4;
    const int wr = w >> 2, wc = w & 3;                    // 2M x 4N waves
    const long rowBase = (long)by * 256;
    const long colBase = (long)bx * 256;
    const int kS = K >> 6;                                // 12 for K=768

    const f32x4 z = {0.f, 0.f, 0.f, 0.f};
    f32x4 acc[8][4];
    #pragma unroll
    for (int m = 0; m < 8; ++m)
        #pragma unroll
        for (int n = 0; n < 4; ++n) acc[m][n] = z;

    // LDS u16 offsets: A half-tile = [128][64] = 8192 u16
    #define AOFF(bi, h) ((bi) * 16384 + (h) * 8192)
    #define BOFF(bi, h) (32768 + (bi) * 16384 + (h) * 8192)

    // stage one half-tile (128 rows x 64 cols) of A or B: 2 G2L/thread
    #define STAGE_A(kt, h) do {                                                     \
        const int k0_ = (kt) << 6, bi_ = (kt) & 1;                                  \
        _Pragma("unroll")                                                           \
        for (int i_ = 0; i_ < 2; ++i_) {                                            \
            const int c_ = i_ * 512 + t, row_ = c_ >> 3, ch_ = c_ & 7;              \
            const int sch_ = ch_ ^ (row_ & 7);                                      \
            G2L(A + (rowBase + (h) * 128 + row_) * K + k0_ + sch_ * 8,              \
                lds + AOFF(bi_, h) + (i_ * 512 + w * 64) * 8);                      \
        }                                                                           \
    } while (0)
    #define STAGE_B(kt, h) do {                                                     \
        const int k0_ = (kt) << 6, bi_ = (kt) & 1;                                  \
        _Pragma("unroll")                                                           \
        for (int i_ = 0; i_ < 2; ++i_) {                                            \
            const int c_ = i_ * 512 + t, row_ = c_ >> 3, ch_ = c_ & 7;              \
            const int sch_ = ch_ ^ (row_ & 7);                                      \
            G2L(B + (colBase + (h) * 128 + row_) * K + k0_ + sch_ * 8,              \
                lds + BOFF(bi_, h) + (i_ * 512 + w * 64) * 8);                      \
        }                                                                           \
    } while (0)

    #define LOAD_AF(q, bufi) do {                                                   \
        _Pragma("unroll")                                                           \
        for (int j_ = 0; j_ < 2; ++j_)                                              \
            _Pragma("unroll")                                                       \
            for (int kk_ = 0; kk_ < 2; ++kk_) {                                     \
                const int hr_ = (2 * (q) + j_) * 16 + lr;                           \
                af[j_][kk_] = *reinterpret_cast<const bf16x8*>(                     \
                    &lds[AOFF(bufi, wr) + hr_ * 64 + (((kk_ * 4 + lg) ^ (hr_ & 7)) << 3)]); \
            }                                                                       \
    } while (0)
    #define LOAD_BF(bufi) do {                                                      \
        _Pragma("unroll")                                                           \
        for (int n_ = 0; n_ < 4; ++n_)                                              \
            _Pragma("unroll")                                                       \
            for (int kk_ = 0; kk_ < 2; ++kk_) {                                     \
                const int hr_ = (wc & 1) * 64 + n_ * 16 + lr;                       \
                bfr[n_][kk_] = *reinterpret_cast<const bf16x8*>(                    \
                    &lds[BOFF(bufi, (wc >> 1)) + hr_ * 64 + (((kk_ * 4 + lg) ^ (hr_ & 7)) << 3)]); \
            }                                                                       \
    } while (0)

    #define BARRIER do { __builtin_amdgcn_sched_barrier(0); __builtin_amdgcn_s_barrier(); \
                         __builtin_amdgcn_sched_barrier(0); } while (0)
    #define LGKM0 do { asm volatile("s_waitcnt lgkmcnt(0)" ::: "memory"); \
                       __builtin_amdgcn_sched_barrier(0); } while (0)
    #define PHASE_MFMA(q) do {                                                      \
        __builtin_amdgcn_s_setprio(1);                                              \
        _Pragma("unroll")                                                           \
        for (int kk_ = 0; kk_ < 2; ++kk_)                                           \
            _Pragma("unroll")                                                       \
            for (int n_ = 0; n_ < 4; ++n_) {                                        \
                acc[2 * (q)][n_]     = mfma16(af[0][kk_], bfr[n_][kk_], acc[2 * (q)][n_]); \
                acc[2 * (q) + 1][n_] = mfma16(af[1][kk_], bfr[n_][kk_], acc[2 * (q) + 1][n_]); \
            }                                                                       \
        __builtin_amdgcn_s_setprio(0);                                              \
    } while (0)

    // prologue: tile0 A+B, tile1 B (12 G2L/thread in flight)
    STAGE_A(0, 0); STAGE_A(0, 1);
    STAGE_B(0, 0); STAGE_B(0, 1);
    STAGE_B(1, 0); STAGE_B(1, 1);

    for (int tt = 0; tt < kS; ++tt) {
        const int cur = tt & 1;
        bf16x8 af[2][2], bfr[4][2];
        // ---- phase 0 ----
        if (tt + 1 < kS) { asm volatile("s_waitcnt vmcnt(4)" ::: "memory"); }
        else             { asm volatile("s_waitcnt vmcnt(0)" ::: "memory"); }
        BARRIER;
        if (tt + 1 < kS) STAGE_A(tt + 1, 0);
        LOAD_BF(cur);
        LOAD_AF(0, cur);
        LGKM0;
        PHASE_MFMA(0);
        // ---- phase 1 ----
        BARRIER;
        if (tt + 1 < kS) STAGE_A(tt + 1, 1);
        LOAD_AF(1, cur);
        LGKM0;
        PHASE_MFMA(1);
        // ---- phase 2 ----
        BARRIER;
        if (tt + 2 < kS) STAGE_B(tt + 2, 0);
        LOAD_AF(2, cur);
        LGKM0;
        PHASE_MFMA(2);
        // ---- phase 3 ----
        BARRIER;
        if (tt + 2 < kS) STAGE_B(tt + 2, 1);
        LOAD_AF(3, cur);
        LGKM0;
        PHASE_MFMA(3);
    }
    #undef STAGE_A
    #undef STAGE_B
    #undef LOAD_AF
    #undef LOAD_BF
    #undef PHASE_MFMA
    #undef BARRIER
    #undef LGKM0
    #undef AOFF
    #undef BOFF

    #pragma unroll
    for (int n = 0; n < 4; ++n) {
        const long gc = colBase + wc * 64 + n * 16 + lr;
        const float bv = bias[gc];
        const float csc = (gc < qcols) ? qsc : 1.0f;
        #pragma unroll
        for (int m = 0; m < 8; ++m) {
            const long gr = rowBase + wr * 128 + m * 16 + lg * 4;
            #pragma unroll
            for (int r = 0; r < 4; ++r) {
                const float v = (acc[m][n][r] + bv) * csc;
                if (OUTF32) reinterpret_cast<float*>(Cp)[(gr + r) * N + gc] = v;
                else        reinterpret_cast<u16*>(Cp)[(gr + r) * N + gc] = f32_to_bf16(v);
            }
        }
    }
}

// ---------------- V transpose with PV k-permutation pi' ----------------
// vt[bh][d][pos p] = V[key = (p>>5)*32 + ((p>>2)&1)*16 + ((p>>3)&3)*4 + (p&3)][d]
__global__ __launch_bounds__(256) void transpose_v_k(const u16* __restrict__ qkv, u16* __restrict__ vt) {
    const int bh = blockIdx.y, b = bh / 12, h = bh % 12;
    const int nt = blockIdx.x;
    __shared__ __align__(16) u16 Ts[64][72];   // [key][d]
    const int t = threadIdx.x;
    const int rr = t >> 2;
    #pragma unroll
    for (int i = 0; i < 2; ++i) {
        const int ch = (t & 3) + i * 4;
        const u16* src = qkv + (long)(b * 1024 + nt * 64 + rr) * 2304 + 1536 + h * 64 + ch * 8;
        *reinterpret_cast<uint4*>(&Ts[rr][ch * 8]) = *reinterpret_cast<const uint4*>(src);
    }
    __syncthreads();
    #pragma unroll
    for (int i = 0; i < 2; ++i) {
        const int ch = (t & 3) + i * 4;   // pos p = ch*8+j
        u16 vals[8];
        #pragma unroll
        for (int j = 0; j < 8; ++j)
            vals[j] = Ts[(ch >> 2) * 32 + (j >> 2) * 16 + (ch & 3) * 4 + (j & 3)][rr];
        u16* dst = vt + (long)(bh * 64 + rr) * 1024 + nt * 64 + ch * 8;
        *reinterpret_cast<uint4*>(dst) = *reinterpret_cast<const uint4*>(vals);
    }
}

// ---------------- flash attention v7: swapped-QK, in-register P, QBLK=128 ----------------
__global__ __launch_bounds__(256, 3) void attn_k(const u16* __restrict__ qkv, const u16* __restrict__ vt,
                                                 u16* __restrict__ outp) {
    const int id = blockIdx.x;
    const int bh = id % 96, qt = id / 96;   // qt in 0..7; same-bh -> same XCD
    const int b = bh / 12, h = bh % 12;
    const int t = threadIdx.x, w = t >> 6, l = t & 63, lr = l & 15, lg = l >> 4;
    __shared__ __align__(16) u16 Ks[2][64 * 64];
    __shared__ __align__(16) u16 Vts[2][64 * 64];   // [d][perm key]

    const u16* kb = qkv + 768 + h * 64;
    const u16* vb = vt + (long)bh * 64 * 1024;

    #pragma unroll
    for (int i = 0; i < 2; ++i) {
        const int c = (i * 4 + w) * 64 + l;
        const int row = c >> 3, sch = (c & 7) ^ (row & 7);
        G2L(kb + (long)(b * 1024 + row) * 2304 + sch * 8, &Ks[0][(i * 4 + w) * 512]);
        G2L(vb + (long)row * 1024 + sch * 8, &Vts[0][(i * 4 + w) * 512]);
    }
    const u16* qb = qkv + (long)(b * 1024 + qt * 128 + w * 32) * 2304 + h * 64;
    bf16x8 aq[2][2];
    #pragma unroll
    for (int qf = 0; qf < 2; ++qf)
        #pragma unroll
        for (int kk = 0; kk < 2; ++kk)
            aq[qf][kk] = *reinterpret_cast<const bf16x8*>(qb + (long)(qf * 16 + lr) * 2304 + (kk * 4 + lg) * 8);

    const f32x4 z = {0.f, 0.f, 0.f, 0.f};
    f32x4 o[2][4];
    f32x4 dacc[2];
    #pragma unroll
    for (int qf = 0; qf < 2; ++qf) {
        #pragma unroll
        for (int n = 0; n < 4; ++n) o[qf][n] = z;
        dacc[qf] = z;
    }
    const unsigned one2 = 0x3F803F80u;
    uint4 onesu = make_uint4(one2, one2, one2, one2);
    const bf16x8 ones = *reinterpret_cast<const bf16x8*>(&onesu);

    #pragma unroll 2
    for (int kt = 0; kt < 16; ++kt) {
        const int cur = kt & 1;
        asm volatile("s_waitcnt vmcnt(0)" ::: "memory");
        __builtin_amdgcn_sched_barrier(0);
        __builtin_amdgcn_s_barrier();
        __builtin_amdgcn_sched_barrier(0);
        if (kt < 15) {
            const int ktn = kt + 1;
            #pragma unroll
            for (int i = 0; i < 2; ++i) {
                const int c = (i * 4 + w) * 64 + l;
                const int row = c >> 3, sch = (c & 7) ^ (row & 7);
                G2L(kb + (long)(b * 1024 + ktn * 64 + row) * 2304 + sch * 8, &Ks[cur ^ 1][(i * 4 + w) * 512]);
                G2L(vb + (long)row * 1024 + ktn * 64 + sch * 8, &Vts[cur ^ 1][(i * 4 + w) * 512]);
            }
        }
        __builtin_amdgcn_sched_barrier(0);
        // S^T = K @ Q^T: s[kc][qf] = S[key=kc*16+lg*4+r][q=qf*16+lr]
        f32x4 s[4][2];
        #pragma unroll
        for (int kc = 0; kc < 4; ++kc)
            #pragma unroll
            for (int qf = 0; qf < 2; ++qf) s[kc][qf] = z;
        #pragma unroll
        for (int kk = 0; kk < 2; ++kk) {
            #pragma unroll
            for (int kc = 0; kc < 4; ++kc) {
                const int row = kc * 16 + lr;
                bf16x8 bk = *reinterpret_cast<const bf16x8*>(&Ks[cur][row * 64 + (((kk * 4 + lg) ^ (lr & 7)) << 3)]);
                s[kc][0] = mfma16(bk, aq[0][kk], s[kc][0]);
                s[kc][1] = mfma16(bk, aq[1][kk], s[kc][1]);
            }
        }
        // softmax-lite in-register: p = exp2(s), pack straight to PV A-operand
        #pragma unroll
        for (int qf = 0; qf < 2; ++qf) {
            float pv[4][4];
            #pragma unroll
            for (int kc = 0; kc < 4; ++kc)
                #pragma unroll
                for (int r = 0; r < 4; ++r)
                    pv[kc][r] = fast_exp2(s[kc][qf][r]);
            uint4 u0, u1;
            u0.x = pack_bf16(pv[0][0], pv[0][1]); u0.y = pack_bf16(pv[0][2], pv[0][3]);
            u0.z = pack_bf16(pv[1][0], pv[1][1]); u0.w = pack_bf16(pv[1][2], pv[1][3]);
            u1.x = pack_bf16(pv[2][0], pv[2][1]); u1.y = pack_bf16(pv[2][2], pv[2][3]);
            u1.z = pack_bf16(pv[3][0], pv[3][1]); u1.w = pack_bf16(pv[3][2], pv[3][3]);
            bf16x8 pa0 = *reinterpret_cast<bf16x8*>(&u0);
            bf16x8 pa1 = *reinterpret_cast<bf16x8*>(&u1);
            dacc[qf] = mfma16(pa0, ones, dacc[qf]);
            dacc[qf] = mfma16(pa1, ones, dacc[qf]);
            #pragma unroll
            for (int kk = 0; kk < 2; ++kk) {
                const bf16x8 pa = kk ? pa1 : pa0;
                const int swzk = ((kk * 4 + lg) ^ (lr & 7)) << 3;
                #pragma unroll
                for (int n = 0; n < 4; ++n) {
                    const int row = n * 16 + lr;
                    bf16x8 vbf = *reinterpret_cast<const bf16x8*>(&Vts[cur][row * 64 + swzk]);
                    o[qf][n] = mfma16(pa, vbf, o[qf][n]);
                }
            }
        }
    }
    #pragma unroll
    for (int qf = 0; qf < 2; ++qf) {
        const int qrow = qt * 128 + w * 32 + qf * 16 + lg * 4;
        #pragma unroll
        for (int r = 0; r < 4; ++r) {
            const float inv = 1.0f / dacc[qf][r];
            #pragma unroll
            for (int n = 0; n < 4; ++n) {
                outp[(long)(b * 1024 + qrow + r) * 768 + h * 64 + n * 16 + lr] =
                    f32_to_bf16(o[qf][n][r] * inv);
            }
        }
    }
}

extern "C" void kernel_launch(void* const* d_in, const int* in_sizes, int n_in,
                              void* d_out, int out_size, void* d_ws, size_t ws_size,
                              hipStream_t stream) {
    (void)in_sizes; (void)n_in; (void)out_size; (void)ws_size;
    const float* x    = (const float*)d_in[0];
    const float* Wqkv = (const float*)d_in[1];
    const float* bqkv = (const float*)d_in[2];
    const float* Wout = (const float*)d_in[3];
    const float* bout = (const float*)d_in[4];

    u16* xb   = (u16*)d_ws;          // 8192*768
    u16* Wqb  = xb  + 6291456;       // 2304*768
    u16* Wob  = Wqb + 1769472;       // 768*768
    u16* qkv  = Wob + 589824;        // 8192*2304
    u16* vtb  = qkv + 18874368;      // 96*64*1024
    u16* attn = vtb + 6291456;       // 8192*768

    const float sc2 = 0.052058773f;  // 768^-0.5 * log2(e)

    cvt3_k<<<8448, 256, 0, stream>>>(x, Wqkv, Wout, xb);

    gemm256_k<0><<<288, 512, 131072, stream>>>(xb, Wqb, bqkv, qkv, 8192, 2304, 768, 9, 768, sc2);
    transpose_v_k<<<dim3(16, 96), 256, 0, stream>>>(qkv, vtb);
    attn_k<<<768, 256, 0, stream>>>(qkv, vtb, attn);
    gemm256_k<1><<<96, 512, 131072, stream>>>(attn, Wob, bout, d_out, 8192, 768, 768, 3, 0, 1.0f);
}

// Round 16
// 122.982 us; speedup vs baseline: 1.3490x; 1.0817x over previous
//
#include <hip/hip_runtime.h>
#include <stdint.h>

typedef __bf16 bf16x8 __attribute__((ext_vector_type(8)));
typedef float  f32x4  __attribute__((ext_vector_type(4)));
typedef unsigned short u16;

#define AS1 __attribute__((address_space(1)))
#define AS3 __attribute__((address_space(3)))
#define G2L(gp, lp) __builtin_amdgcn_global_load_lds( \
    (const AS1 unsigned int*)(uintptr_t)(gp), \
    (AS3 unsigned int*)(uintptr_t)(lp), 16, 0, 0)

static __device__ __forceinline__ u16 f32_to_bf16(float f) {
    unsigned u = __float_as_uint(f);
    u += 0x7fffu + ((u >> 16) & 1u);
    return (u16)(u >> 16);
}

static __device__ __forceinline__ unsigned pack_bf16(float lo, float hi) {
    return (unsigned)f32_to_bf16(lo) | ((unsigned)f32_to_bf16(hi) << 16);
}

static __device__ __forceinline__ float fast_exp2(float x) {
    return __builtin_amdgcn_exp2f(x);
}

static __device__ __forceinline__ f32x4 mfma16(bf16x8 a, bf16x8 b, f32x4 c) {
    return __builtin_amdgcn_mfma_f32_16x16x32_bf16(a, b, c, 0, 0, 0);
}

// ---------------- fused fp32 -> bf16 convert for x, W_qkv, W_out ----------------
__global__ void cvt3_k(const float* __restrict__ a, const float* __restrict__ b,
                       const float* __restrict__ c, u16* __restrict__ out) {
    const int i = blockIdx.x * blockDim.x + threadIdx.x;   // vec4 index
    const float* src; int off;
    if (i < 1572864)      { src = a; off = 0; }
    else if (i < 2015232) { src = b; off = 1572864; }
    else                  { src = c; off = 2015232; }
    const float4 v = reinterpret_cast<const float4*>(src)[i - off];
    reinterpret_cast<uint2*>(out)[i] = make_uint2(pack_bf16(v.x, v.y), pack_bf16(v.z, v.w));
}

// ---------------- bf16 GEMM 256x256 v2: template-faithful 4-phase/K-tile ----------------
// Key fix vs R15: ds_reads issue BEFORE the phase barrier (overlap barrier skew +
// prior phase's MFMA backlog); TWO barriers per phase (template pacing); vmcnt
// ledger at end-of-tile ph3 (keep B(tt+2)'s 4 loads in flight, never drain to 0
// mid-loop). 512 thr = 8 waves (2Mx4N), per-wave out 128x64 (8x4 frags), BK=64.
template<int OUTF32>
__global__ __launch_bounds__(512, 1) void gemm256_k(const u16* __restrict__ A, const u16* __restrict__ B,
                                                    const float* __restrict__ bias, void* __restrict__ Cp,
                                                    int M, int N, int K, int nbx, int qcols, float qsc) {
    extern __shared__ __align__(16) u16 lds[];
    const int id = blockIdx.x;
    const int cpx = gridDim.x >> 3;
    const int swz = (id & 7) * cpx + (id >> 3);
    const int bx = swz % nbx, by = swz / nbx;
    const int t = threadIdx.x;
    const int w = t >> 6, l = t & 63, lr = l & 15, lg = l >> 4;
    const int wr = w >> 2, wc = w & 3;
    const long rowBase = (long)by * 256;
    const long colBase = (long)bx * 256;
    const int kS = K >> 6;

    const f32x4 z = {0.f, 0.f, 0.f, 0.f};
    f32x4 acc[8][4];
    #pragma unroll
    for (int m = 0; m < 8; ++m)
        #pragma unroll
        for (int n = 0; n < 4; ++n) acc[m][n] = z;

    #define AOFF(bi, h) ((bi) * 16384 + (h) * 8192)
    #define BOFF(bi, h) (32768 + (bi) * 16384 + (h) * 8192)

    #define STAGE_A(kt, h) do {                                                     \
        const int k0_ = (kt) << 6, bi_ = (kt) & 1;                                  \
        _Pragma("unroll")                                                           \
        for (int i_ = 0; i_ < 2; ++i_) {                                            \
            const int c_ = i_ * 512 + t, row_ = c_ >> 3, ch_ = c_ & 7;              \
            const int sch_ = ch_ ^ (row_ & 7);                                      \
            G2L(A + (rowBase + (h) * 128 + row_) * K + k0_ + sch_ * 8,              \
                lds + AOFF(bi_, h) + (i_ * 512 + w * 64) * 8);                      \
        }                                                                           \
    } while (0)
    #define STAGE_B(kt, h) do {                                                     \
        const int k0_ = (kt) << 6, bi_ = (kt) & 1;                                  \
        _Pragma("unroll")                                                           \
        for (int i_ = 0; i_ < 2; ++i_) {                                            \
            const int c_ = i_ * 512 + t, row_ = c_ >> 3, ch_ = c_ & 7;              \
            const int sch_ = ch_ ^ (row_ & 7);                                      \
            G2L(B + (colBase + (h) * 128 + row_) * K + k0_ + sch_ * 8,              \
                lds + BOFF(bi_, h) + (i_ * 512 + w * 64) * 8);                      \
        }                                                                           \
    } while (0)

    #define LOAD_AF(q, bufi) do {                                                   \
        _Pragma("unroll")                                                           \
        for (int j_ = 0; j_ < 2; ++j_)                                              \
            _Pragma("unroll")                                                       \
            for (int kk_ = 0; kk_ < 2; ++kk_) {                                     \
                const int hr_ = (2 * (q) + j_) * 16 + lr;                           \
                af[j_][kk_] = *reinterpret_cast<const bf16x8*>(                     \
                    &lds[AOFF(bufi, wr) + hr_ * 64 + (((kk_ * 4 + lg) ^ (hr_ & 7)) << 3)]); \
            }                                                                       \
    } while (0)
    #define LOAD_BF(bufi) do {                                                      \
        _Pragma("unroll")                                                           \
        for (int n_ = 0; n_ < 4; ++n_)                                              \
            _Pragma("unroll")                                                       \
            for (int kk_ = 0; kk_ < 2; ++kk_) {                                     \
                const int hr_ = (wc & 1) * 64 + n_ * 16 + lr;                       \
                bfr[n_][kk_] = *reinterpret_cast<const bf16x8*>(                    \
                    &lds[BOFF(bufi, (wc >> 1)) + hr_ * 64 + (((kk_ * 4 + lg) ^ (hr_ & 7)) << 3)]); \
            }                                                                       \
    } while (0)

    #define SBAR do { __builtin_amdgcn_sched_barrier(0); __builtin_amdgcn_s_barrier(); \
                      __builtin_amdgcn_sched_barrier(0); } while (0)
    #define LGKM0 do { asm volatile("s_waitcnt lgkmcnt(0)" ::: "memory"); \
                       __builtin_amdgcn_sched_barrier(0); } while (0)
    #define PHASE_MFMA(q) do {                                                      \
        __builtin_amdgcn_s_setprio(1);                                              \
        _Pragma("unroll")                                                           \
        for (int kk_ = 0; kk_ < 2; ++kk_)                                           \
            _Pragma("unroll")                                                       \
            for (int n_ = 0; n_ < 4; ++n_) {                                        \
                acc[2 * (q)][n_]     = mfma16(af[0][kk_], bfr[n_][kk_], acc[2 * (q)][n_]); \
                acc[2 * (q) + 1][n_] = mfma16(af[1][kk_], bfr[n_][kk_], acc[2 * (q) + 1][n_]); \
            }                                                                       \
        __builtin_amdgcn_s_setprio(0);                                              \
    } while (0)

    // prologue: tile0 A+B, tile1 B; drain tile0 (keep B(1)); barrier
    STAGE_A(0, 0); STAGE_A(0, 1);
    STAGE_B(0, 0); STAGE_B(0, 1);
    if (kS > 1) { STAGE_B(1, 0); STAGE_B(1, 1); }
    if (kS > 1) asm volatile("s_waitcnt vmcnt(4)" ::: "memory");
    else        asm volatile("s_waitcnt vmcnt(0)" ::: "memory");
    SBAR;

    for (int tt = 0; tt < kS; ++tt) {
        const int cur = tt & 1;
        bf16x8 af[2][2], bfr[4][2];
        // ---- phase 0: reads pre-barrier, stage A(tt+1,0) ----
        LOAD_BF(cur);
        LOAD_AF(0, cur);
        if (tt + 1 < kS) STAGE_A(tt + 1, 0);
        SBAR;
        LGKM0;
        PHASE_MFMA(0);
        SBAR;
        // ---- phase 1 ----
        LOAD_AF(1, cur);
        if (tt + 1 < kS) STAGE_A(tt + 1, 1);
        SBAR;
        LGKM0;
        PHASE_MFMA(1);
        SBAR;
        // ---- phase 2 ----
        LOAD_AF(2, cur);
        if (tt + 2 < kS) STAGE_B(tt + 2, 0);
        SBAR;
        LGKM0;
        PHASE_MFMA(2);
        SBAR;
        // ---- phase 3 + end-of-tile vmcnt (keep B(tt+2) in flight) ----
        LOAD_AF(3, cur);
        if (tt + 2 < kS) STAGE_B(tt + 2, 1);
        SBAR;
        LGKM0;
        PHASE_MFMA(3);
        if (tt + 2 < kS) asm volatile("s_waitcnt vmcnt(4)" ::: "memory");
        else             asm volatile("s_waitcnt vmcnt(0)" ::: "memory");
        SBAR;
    }
    #undef STAGE_A
    #undef STAGE_B
    #undef LOAD_AF
    #undef LOAD_BF
    #undef PHASE_MFMA
    #undef SBAR
    #undef LGKM0
    #undef AOFF
    #undef BOFF

    #pragma unroll
    for (int n = 0; n < 4; ++n) {
        const long gc = colBase + wc * 64 + n * 16 + lr;
        const float bv = bias[gc];
        const float csc = (gc < qcols) ? qsc : 1.0f;
        #pragma unroll
        for (int m = 0; m < 8; ++m) {
            const long gr = rowBase + wr * 128 + m * 16 + lg * 4;
            #pragma unroll
            for (int r = 0; r < 4; ++r) {
                const float v = (acc[m][n][r] + bv) * csc;
                if (OUTF32) reinterpret_cast<float*>(Cp)[(gr + r) * N + gc] = v;
                else        reinterpret_cast<u16*>(Cp)[(gr + r) * N + gc] = f32_to_bf16(v);
            }
        }
    }
}

// ---------------- bf16 GEMM 128x128 (R10-proven 2-phase) for gemm2 ----------------
template<int OUTF32>
__global__ __launch_bounds__(256, 2) void gemm_bt_k(const u16* __restrict__ A, const u16* __restrict__ B,
                                                    const float* __restrict__ bias, void* __restrict__ Cp,
                                                    int M, int N, int K, int nbx, int qcols, float qsc) {
    __shared__ __align__(16) u16 As[2][128 * 64];
    __shared__ __align__(16) u16 Bs[2][128 * 64];
    const int id = blockIdx.x;
    const int cpx = gridDim.x >> 3;
    const int swz = (id & 7) * cpx + (id >> 3);
    const int bx = swz % nbx, by = swz / nbx;
    const int t = threadIdx.x, w = t >> 6, l = t & 63, lr = l & 15, lg = l >> 4;
    const int wr = w >> 1, wc = w & 1;
    const long rowBase = (long)by * 128;
    const long colBase = (long)bx * 128;

    const f32x4 z = {0.f, 0.f, 0.f, 0.f};
    f32x4 acc[4][4];
    #pragma unroll
    for (int m = 0; m < 4; ++m)
        #pragma unroll
        for (int n = 0; n < 4; ++n) acc[m][n] = z;

    const int kSteps = K >> 6;
    #pragma unroll
    for (int i = 0; i < 4; ++i) {
        const int c = i * 256 + t, row = c >> 3, ch = c & 7;
        const int sch = ch ^ (row & 7);
        G2L(A + (rowBase + row) * K + sch * 8, &As[0][(i * 256 + w * 64) * 8]);
        G2L(B + (colBase + row) * K + sch * 8, &Bs[0][(i * 256 + w * 64) * 8]);
    }
    for (int kt = 0; kt < kSteps; ++kt) {
        const int cur = kt & 1;
        asm volatile("s_waitcnt vmcnt(0)" ::: "memory");
        __builtin_amdgcn_sched_barrier(0);
        __builtin_amdgcn_s_barrier();
        __builtin_amdgcn_sched_barrier(0);
        if (kt + 1 < kSteps) {
            const int k0 = (kt + 1) << 6;
            #pragma unroll
            for (int i = 0; i < 4; ++i) {
                const int c = i * 256 + t, row = c >> 3, ch = c & 7;
                const int sch = ch ^ (row & 7);
                G2L(A + (rowBase + row) * K + k0 + sch * 8, &As[cur ^ 1][(i * 256 + w * 64) * 8]);
                G2L(B + (colBase + row) * K + k0 + sch * 8, &Bs[cur ^ 1][(i * 256 + w * 64) * 8]);
            }
        }
        __builtin_amdgcn_sched_barrier(0);
        #pragma unroll
        for (int kk = 0; kk < 2; ++kk) {
            bf16x8 af[4], bfr[4];
            #pragma unroll
            for (int m = 0; m < 4; ++m) {
                const int row = wr * 64 + m * 16 + lr;
                af[m] = *reinterpret_cast<const bf16x8*>(&As[cur][row * 64 + (((kk * 4 + lg) ^ (lr & 7)) << 3)]);
            }
            #pragma unroll
            for (int n = 0; n < 4; ++n) {
                const int row = wc * 64 + n * 16 + lr;
                bfr[n] = *reinterpret_cast<const bf16x8*>(&Bs[cur][row * 64 + (((kk * 4 + lg) ^ (lr & 7)) << 3)]);
            }
            #pragma unroll
            for (int m = 0; m < 4; ++m)
                #pragma unroll
                for (int n = 0; n < 4; ++n) acc[m][n] = mfma16(af[m], bfr[n], acc[m][n]);
        }
    }
    #pragma unroll
    for (int n = 0; n < 4; ++n) {
        const long gc = colBase + wc * 64 + n * 16 + lr;
        const float bv = bias[gc];
        const float csc = (gc < qcols) ? qsc : 1.0f;
        #pragma unroll
        for (int m = 0; m < 4; ++m) {
            const long gr = rowBase + wr * 64 + m * 16 + lg * 4;
            #pragma unroll
            for (int r = 0; r < 4; ++r) {
                const float v = (acc[m][n][r] + bv) * csc;
                if (OUTF32) reinterpret_cast<float*>(Cp)[(gr + r) * N + gc] = v;
                else        reinterpret_cast<u16*>(Cp)[(gr + r) * N + gc] = f32_to_bf16(v);
            }
        }
    }
}

// ---------------- V transpose with PV k-permutation pi' ----------------
// vt[bh][d][pos p] = V[key = (p>>5)*32 + ((p>>2)&1)*16 + ((p>>3)&3)*4 + (p&3)][d]
__global__ __launch_bounds__(256) void transpose_v_k(const u16* __restrict__ qkv, u16* __restrict__ vt) {
    const int bh = blockIdx.y, b = bh / 12, h = bh % 12;
    const int nt = blockIdx.x;
    __shared__ __align__(16) u16 Ts[64][72];   // [key][d]
    const int t = threadIdx.x;
    const int rr = t >> 2;
    #pragma unroll
    for (int i = 0; i < 2; ++i) {
        const int ch = (t & 3) + i * 4;
        const u16* src = qkv + (long)(b * 1024 + nt * 64 + rr) * 2304 + 1536 + h * 64 + ch * 8;
        *reinterpret_cast<uint4*>(&Ts[rr][ch * 8]) = *reinterpret_cast<const uint4*>(src);
    }
    __syncthreads();
    #pragma unroll
    for (int i = 0; i < 2; ++i) {
        const int ch = (t & 3) + i * 4;   // pos p = ch*8+j
        u16 vals[8];
        #pragma unroll
        for (int j = 0; j < 8; ++j)
            vals[j] = Ts[(ch >> 2) * 32 + (j >> 2) * 16 + (ch & 3) * 4 + (j & 3)][rr];
        u16* dst = vt + (long)(bh * 64 + rr) * 1024 + nt * 64 + ch * 8;
        *reinterpret_cast<uint4*>(dst) = *reinterpret_cast<const uint4*>(vals);
    }
}

// ---------------- flash attention v7: swapped-QK, in-register P, QBLK=128 ----------------
__global__ __launch_bounds__(256, 3) void attn_k(const u16* __restrict__ qkv, const u16* __restrict__ vt,
                                                 u16* __restrict__ outp) {
    const int id = blockIdx.x;
    const int bh = id % 96, qt = id / 96;   // qt in 0..7; same-bh -> same XCD
    const int b = bh / 12, h = bh % 12;
    const int t = threadIdx.x, w = t >> 6, l = t & 63, lr = l & 15, lg = l >> 4;
    __shared__ __align__(16) u16 Ks[2][64 * 64];
    __shared__ __align__(16) u16 Vts[2][64 * 64];   // [d][perm key]

    const u16* kb = qkv + 768 + h * 64;
    const u16* vb = vt + (long)bh * 64 * 1024;

    #pragma unroll
    for (int i = 0; i < 2; ++i) {
        const int c = (i * 4 + w) * 64 + l;
        const int row = c >> 3, sch = (c & 7) ^ (row & 7);
        G2L(kb + (long)(b * 1024 + row) * 2304 + sch * 8, &Ks[0][(i * 4 + w) * 512]);
        G2L(vb + (long)row * 1024 + sch * 8, &Vts[0][(i * 4 + w) * 512]);
    }
    const u16* qb = qkv + (long)(b * 1024 + qt * 128 + w * 32) * 2304 + h * 64;
    bf16x8 aq[2][2];
    #pragma unroll
    for (int qf = 0; qf < 2; ++qf)
        #pragma unroll
        for (int kk = 0; kk < 2; ++kk)
            aq[qf][kk] = *reinterpret_cast<const bf16x8*>(qb + (long)(qf * 16 + lr) * 2304 + (kk * 4 + lg) * 8);

    const f32x4 z = {0.f, 0.f, 0.f, 0.f};
    f32x4 o[2][4];
    f32x4 dacc[2];
    #pragma unroll
    for (int qf = 0; qf < 2; ++qf) {
        #pragma unroll
        for (int n = 0; n < 4; ++n) o[qf][n] = z;
        dacc[qf] = z;
    }
    const unsigned one2 = 0x3F803F80u;
    uint4 onesu = make_uint4(one2, one2, one2, one2);
    const bf16x8 ones = *reinterpret_cast<const bf16x8*>(&onesu);

    #pragma unroll 2
    for (int kt = 0; kt < 16; ++kt) {
        const int cur = kt & 1;
        asm volatile("s_waitcnt vmcnt(0)" ::: "memory");
        __builtin_amdgcn_sched_barrier(0);
        __builtin_amdgcn_s_barrier();
        __builtin_amdgcn_sched_barrier(0);
        if (kt < 15) {
            const int ktn = kt + 1;
            #pragma unroll
            for (int i = 0; i < 2; ++i) {
                const int c = (i * 4 + w) * 64 + l;
                const int row = c >> 3, sch = (c & 7) ^ (row & 7);
                G2L(kb + (long)(b * 1024 + ktn * 64 + row) * 2304 + sch * 8, &Ks[cur ^ 1][(i * 4 + w) * 512]);
                G2L(vb + (long)row * 1024 + ktn * 64 + sch * 8, &Vts[cur ^ 1][(i * 4 + w) * 512]);
            }
        }
        __builtin_amdgcn_sched_barrier(0);
        // S^T = K @ Q^T: s[kc][qf] = S[key=kc*16+lg*4+r][q=qf*16+lr]
        f32x4 s[4][2];
        #pragma unroll
        for (int kc = 0; kc < 4; ++kc)
            #pragma unroll
            for (int qf = 0; qf < 2; ++qf) s[kc][qf] = z;
        #pragma unroll
        for (int kk = 0; kk < 2; ++kk) {
            #pragma unroll
            for (int kc = 0; kc < 4; ++kc) {
                const int row = kc * 16 + lr;
                bf16x8 bk = *reinterpret_cast<const bf16x8*>(&Ks[cur][row * 64 + (((kk * 4 + lg) ^ (lr & 7)) << 3)]);
                s[kc][0] = mfma16(bk, aq[0][kk], s[kc][0]);
                s[kc][1] = mfma16(bk, aq[1][kk], s[kc][1]);
            }
        }
        // softmax-lite in-register: p = exp2(s), pack straight to PV A-operand
        #pragma unroll
        for (int qf = 0; qf < 2; ++qf) {
            float pv[4][4];
            #pragma unroll
            for (int kc = 0; kc < 4; ++kc)
                #pragma unroll
                for (int r = 0; r < 4; ++r)
                    pv[kc][r] = fast_exp2(s[kc][qf][r]);
            uint4 u0, u1;
            u0.x = pack_bf16(pv[0][0], pv[0][1]); u0.y = pack_bf16(pv[0][2], pv[0][3]);
            u0.z = pack_bf16(pv[1][0], pv[1][1]); u0.w = pack_bf16(pv[1][2], pv[1][3]);
            u1.x = pack_bf16(pv[2][0], pv[2][1]); u1.y = pack_bf16(pv[2][2], pv[2][3]);
            u1.z = pack_bf16(pv[3][0], pv[3][1]); u1.w = pack_bf16(pv[3][2], pv[3][3]);
            bf16x8 pa0 = *reinterpret_cast<bf16x8*>(&u0);
            bf16x8 pa1 = *reinterpret_cast<bf16x8*>(&u1);
            dacc[qf] = mfma16(pa0, ones, dacc[qf]);
            dacc[qf] = mfma16(pa1, ones, dacc[qf]);
            #pragma unroll
            for (int kk = 0; kk < 2; ++kk) {
                const bf16x8 pa = kk ? pa1 : pa0;
                const int swzk = ((kk * 4 + lg) ^ (lr & 7)) << 3;
                #pragma unroll
                for (int n = 0; n < 4; ++n) {
                    const int row = n * 16 + lr;
                    bf16x8 vbf = *reinterpret_cast<const bf16x8*>(&Vts[cur][row * 64 + swzk]);
                    o[qf][n] = mfma16(pa, vbf, o[qf][n]);
                }
            }
        }
    }
    #pragma unroll
    for (int qf = 0; qf < 2; ++qf) {
        const int qrow = qt * 128 + w * 32 + qf * 16 + lg * 4;
        #pragma unroll
        for (int r = 0; r < 4; ++r) {
            const float inv = 1.0f / dacc[qf][r];
            #pragma unroll
            for (int n = 0; n < 4; ++n) {
                outp[(long)(b * 1024 + qrow + r) * 768 + h * 64 + n * 16 + lr] =
                    f32_to_bf16(o[qf][n][r] * inv);
            }
        }
    }
}

extern "C" void kernel_launch(void* const* d_in, const int* in_sizes, int n_in,
                              void* d_out, int out_size, void* d_ws, size_t ws_size,
                              hipStream_t stream) {
    (void)in_sizes; (void)n_in; (void)out_size; (void)ws_size;
    const float* x    = (const float*)d_in[0];
    const float* Wqkv = (const float*)d_in[1];
    const float* bqkv = (const float*)d_in[2];
    const float* Wout = (const float*)d_in[3];
    const float* bout = (const float*)d_in[4];

    u16* xb   = (u16*)d_ws;          // 8192*768
    u16* Wqb  = xb  + 6291456;       // 2304*768
    u16* Wob  = Wqb + 1769472;       // 768*768
    u16* qkv  = Wob + 589824;        // 8192*2304
    u16* vtb  = qkv + 18874368;      // 96*64*1024
    u16* attn = vtb + 6291456;       // 8192*768

    const float sc2 = 0.052058773f;  // 768^-0.5 * log2(e)

    cvt3_k<<<8448, 256, 0, stream>>>(x, Wqkv, Wout, xb);

    gemm256_k<0><<<288, 512, 131072, stream>>>(xb, Wqb, bqkv, qkv, 8192, 2304, 768, 9, 768, sc2);
    transpose_v_k<<<dim3(16, 96), 256, 0, stream>>>(qkv, vtb);
    attn_k<<<768, 256, 0, stream>>>(qkv, vtb, attn);
    gemm_bt_k<1><<<384, 256, 0, stream>>>(attn, Wob, bout, d_out, 8192, 768, 768, 6, 0, 1.0f);
}

// Round 17
// 111.842 us; speedup vs baseline: 1.4833x; 1.0996x over previous
//
#include <hip/hip_runtime.h>
#include <stdint.h>

typedef __bf16 bf16x8 __attribute__((ext_vector_type(8)));
typedef float  f32x4  __attribute__((ext_vector_type(4)));
typedef unsigned short u16;

#define AS1 __attribute__((address_space(1)))
#define AS3 __attribute__((address_space(3)))
#define G2L(gp, lp) __builtin_amdgcn_global_load_lds( \
    (const AS1 unsigned int*)(uintptr_t)(gp), \
    (AS3 unsigned int*)(uintptr_t)(lp), 16, 0, 0)

static __device__ __forceinline__ u16 f32_to_bf16(float f) {
    unsigned u = __float_as_uint(f);
    u += 0x7fffu + ((u >> 16) & 1u);
    return (u16)(u >> 16);
}

static __device__ __forceinline__ unsigned pack_bf16(float lo, float hi) {
    return (unsigned)f32_to_bf16(lo) | ((unsigned)f32_to_bf16(hi) << 16);
}

static __device__ __forceinline__ float fast_exp2(float x) {
    return __builtin_amdgcn_exp2f(x);
}

static __device__ __forceinline__ f32x4 mfma16(bf16x8 a, bf16x8 b, f32x4 c) {
    return __builtin_amdgcn_mfma_f32_16x16x32_bf16(a, b, c, 0, 0, 0);
}

// ---------------- fused fp32 -> bf16 convert for x, W_qkv, W_out ----------------
__global__ void cvt3_k(const float* __restrict__ a, const float* __restrict__ b,
                       const float* __restrict__ c, u16* __restrict__ out) {
    const int i = blockIdx.x * blockDim.x + threadIdx.x;   // vec4 index
    const float* src; int off;
    if (i < 1572864)      { src = a; off = 0; }
    else if (i < 2015232) { src = b; off = 1572864; }
    else                  { src = c; off = 2015232; }
    const float4 v = reinterpret_cast<const float4*>(src)[i - off];
    reinterpret_cast<uint2*>(out)[i] = make_uint2(pack_bf16(v.x, v.y), pack_bf16(v.z, v.w));
}

// ---------------- bf16 GEMM (R10-proven 2-phase 128x128) + fused V-transpose ----------------
// C[M,N] = A[M,K] @ B[N,K]^T + bias. BK=64, dbuf LDS, counted barrier schedule,
// 0-conflict swizzle, XCD-swizzled grid. Columns gc < qcols scaled by qsc.
// If vtp != nullptr, columns gc >= 1536 (the V slice) are written TRANSPOSED
// with the PV k-permutation pi' directly to vt[bh][d][n] (uint2-packed), and
// skipped in the normal C output -> the separate transpose kernel disappears.
// pi': key k (bits k5,k4,k32,k10) -> pos p = k5*32 + k32*8 + k4*4 + k10.
template<int OUTF32>
__global__ __launch_bounds__(256, 2) void gemm_bt_k(const u16* __restrict__ A, const u16* __restrict__ B,
                                                    const float* __restrict__ bias, void* __restrict__ Cp,
                                                    u16* __restrict__ vtp,
                                                    int M, int N, int K, int nbx, int qcols, float qsc) {
    __shared__ __align__(16) u16 As[2][128 * 64];
    __shared__ __align__(16) u16 Bs[2][128 * 64];
    const int id = blockIdx.x;
    const int cpx = gridDim.x >> 3;
    const int swz = (id & 7) * cpx + (id >> 3);
    const int bx = swz % nbx, by = swz / nbx;
    const int t = threadIdx.x, w = t >> 6, l = t & 63, lr = l & 15, lg = l >> 4;
    const int wr = w >> 1, wc = w & 1;
    const long rowBase = (long)by * 128;
    const long colBase = (long)bx * 128;

    const f32x4 z = {0.f, 0.f, 0.f, 0.f};
    f32x4 acc[4][4];
    #pragma unroll
    for (int m = 0; m < 4; ++m)
        #pragma unroll
        for (int n = 0; n < 4; ++n) acc[m][n] = z;

    const int kSteps = K >> 6;
    #pragma unroll
    for (int i = 0; i < 4; ++i) {
        const int c = i * 256 + t, row = c >> 3, ch = c & 7;
        const int sch = ch ^ (row & 7);
        G2L(A + (rowBase + row) * K + sch * 8, &As[0][(i * 256 + w * 64) * 8]);
        G2L(B + (colBase + row) * K + sch * 8, &Bs[0][(i * 256 + w * 64) * 8]);
    }
    for (int kt = 0; kt < kSteps; ++kt) {
        const int cur = kt & 1;
        asm volatile("s_waitcnt vmcnt(0)" ::: "memory");
        __builtin_amdgcn_sched_barrier(0);
        __builtin_amdgcn_s_barrier();
        __builtin_amdgcn_sched_barrier(0);
        if (kt + 1 < kSteps) {
            const int k0 = (kt + 1) << 6;
            #pragma unroll
            for (int i = 0; i < 4; ++i) {
                const int c = i * 256 + t, row = c >> 3, ch = c & 7;
                const int sch = ch ^ (row & 7);
                G2L(A + (rowBase + row) * K + k0 + sch * 8, &As[cur ^ 1][(i * 256 + w * 64) * 8]);
                G2L(B + (colBase + row) * K + k0 + sch * 8, &Bs[cur ^ 1][(i * 256 + w * 64) * 8]);
            }
        }
        __builtin_amdgcn_sched_barrier(0);
        #pragma unroll
        for (int kk = 0; kk < 2; ++kk) {
            bf16x8 af[4], bfr[4];
            #pragma unroll
            for (int m = 0; m < 4; ++m) {
                const int row = wr * 64 + m * 16 + lr;
                af[m] = *reinterpret_cast<const bf16x8*>(&As[cur][row * 64 + (((kk * 4 + lg) ^ (lr & 7)) << 3)]);
            }
            #pragma unroll
            for (int n = 0; n < 4; ++n) {
                const int row = wc * 64 + n * 16 + lr;
                bfr[n] = *reinterpret_cast<const bf16x8*>(&Bs[cur][row * 64 + (((kk * 4 + lg) ^ (lr & 7)) << 3)]);
            }
            #pragma unroll
            for (int m = 0; m < 4; ++m)
                #pragma unroll
                for (int n = 0; n < 4; ++n) acc[m][n] = mfma16(af[m], bfr[n], acc[m][n]);
        }
    }
    #pragma unroll
    for (int n = 0; n < 4; ++n) {
        const long gc = colBase + wc * 64 + n * 16 + lr;
        const float bv = bias[gc];
        const float csc = (gc < qcols) ? qsc : 1.0f;
        #pragma unroll
        for (int m = 0; m < 4; ++m) {
            const long gr0 = rowBase + wr * 64 + m * 16 + lg * 4;
            if (vtp != nullptr && gc >= 1536) {
                // fused V-transpose write: vt[(b*12+h)*64 + d][n] with pi'
                const int hh = (int)(gc - 1536) >> 6;
                const int dd = (int)(gc - 1536) & 63;
                const long bb = gr0 >> 10;
                const int t64 = (int)((gr0 & 1023) >> 6);      // = (by%8)*2 + wr
                const int pbase = (m >> 1) * 32 + lg * 8 + (m & 1) * 4;
                const unsigned w0 = pack_bf16(acc[m][n][0] + bv, acc[m][n][1] + bv);
                const unsigned w1 = pack_bf16(acc[m][n][2] + bv, acc[m][n][3] + bv);
                u16* dst = vtp + ((bb * 12 + hh) * 64 + dd) * 1024L + t64 * 64 + pbase;
                *reinterpret_cast<uint2*>(dst) = make_uint2(w0, w1);
            } else {
                #pragma unroll
                for (int r = 0; r < 4; ++r) {
                    const float v = (acc[m][n][r] + bv) * csc;
                    if (OUTF32) reinterpret_cast<float*>(Cp)[(gr0 + r) * N + gc] = v;
                    else        reinterpret_cast<u16*>(Cp)[(gr0 + r) * N + gc] = f32_to_bf16(v);
                }
            }
        }
    }
}

// ---------------- flash attention v7: swapped-QK, in-register P, QBLK=128 ----------------
// occupancy 4 blocks/CU (32KB LDS); K/V G2L dbuf; denominator via ones-MFMA;
// Q pre-scaled by 768^-0.5*log2e in gemm1 epilogue.
__global__ __launch_bounds__(256, 4) void attn_k(const u16* __restrict__ qkv, const u16* __restrict__ vt,
                                                 u16* __restrict__ outp) {
    const int id = blockIdx.x;
    const int bh = id % 96, qt = id / 96;   // qt in 0..7; same-bh -> same XCD
    const int b = bh / 12, h = bh % 12;
    const int t = threadIdx.x, w = t >> 6, l = t & 63, lr = l & 15, lg = l >> 4;
    __shared__ __align__(16) u16 Ks[2][64 * 64];
    __shared__ __align__(16) u16 Vts[2][64 * 64];   // [d][perm key]

    const u16* kb = qkv + 768 + h * 64;
    const u16* vb = vt + (long)bh * 64 * 1024;

    #pragma unroll
    for (int i = 0; i < 2; ++i) {
        const int c = (i * 4 + w) * 64 + l;
        const int row = c >> 3, sch = (c & 7) ^ (row & 7);
        G2L(kb + (long)(b * 1024 + row) * 2304 + sch * 8, &Ks[0][(i * 4 + w) * 512]);
        G2L(vb + (long)row * 1024 + sch * 8, &Vts[0][(i * 4 + w) * 512]);
    }
    const u16* qb = qkv + (long)(b * 1024 + qt * 128 + w * 32) * 2304 + h * 64;
    bf16x8 aq[2][2];
    #pragma unroll
    for (int qf = 0; qf < 2; ++qf)
        #pragma unroll
        for (int kk = 0; kk < 2; ++kk)
            aq[qf][kk] = *reinterpret_cast<const bf16x8*>(qb + (long)(qf * 16 + lr) * 2304 + (kk * 4 + lg) * 8);

    const f32x4 z = {0.f, 0.f, 0.f, 0.f};
    f32x4 o[2][4];
    f32x4 dacc[2];
    #pragma unroll
    for (int qf = 0; qf < 2; ++qf) {
        #pragma unroll
        for (int n = 0; n < 4; ++n) o[qf][n] = z;
        dacc[qf] = z;
    }
    const unsigned one2 = 0x3F803F80u;
    uint4 onesu = make_uint4(one2, one2, one2, one2);
    const bf16x8 ones = *reinterpret_cast<const bf16x8*>(&onesu);

    #pragma unroll 2
    for (int kt = 0; kt < 16; ++kt) {
        const int cur = kt & 1;
        asm volatile("s_waitcnt vmcnt(0)" ::: "memory");
        __builtin_amdgcn_sched_barrier(0);
        __builtin_amdgcn_s_barrier();
        __builtin_amdgcn_sched_barrier(0);
        if (kt < 15) {
            const int ktn = kt + 1;
            #pragma unroll
            for (int i = 0; i < 2; ++i) {
                const int c = (i * 4 + w) * 64 + l;
                const int row = c >> 3, sch = (c & 7) ^ (row & 7);
                G2L(kb + (long)(b * 1024 + ktn * 64 + row) * 2304 + sch * 8, &Ks[cur ^ 1][(i * 4 + w) * 512]);
                G2L(vb + (long)row * 1024 + ktn * 64 + sch * 8, &Vts[cur ^ 1][(i * 4 + w) * 512]);
            }
        }
        __builtin_amdgcn_sched_barrier(0);
        // S^T = K @ Q^T: s[kc][qf] = S[key=kc*16+lg*4+r][q=qf*16+lr]
        f32x4 s[4][2];
        #pragma unroll
        for (int kc = 0; kc < 4; ++kc)
            #pragma unroll
            for (int qf = 0; qf < 2; ++qf) s[kc][qf] = z;
        #pragma unroll
        for (int kk = 0; kk < 2; ++kk) {
            #pragma unroll
            for (int kc = 0; kc < 4; ++kc) {
                const int row = kc * 16 + lr;
                bf16x8 bk = *reinterpret_cast<const bf16x8*>(&Ks[cur][row * 64 + (((kk * 4 + lg) ^ (lr & 7)) << 3)]);
                s[kc][0] = mfma16(bk, aq[0][kk], s[kc][0]);
                s[kc][1] = mfma16(bk, aq[1][kk], s[kc][1]);
            }
        }
        // softmax-lite in-register: p = exp2(s), pack straight to PV A-operand
        #pragma unroll
        for (int qf = 0; qf < 2; ++qf) {
            float pv[4][4];
            #pragma unroll
            for (int kc = 0; kc < 4; ++kc)
                #pragma unroll
                for (int r = 0; r < 4; ++r)
                    pv[kc][r] = fast_exp2(s[kc][qf][r]);
            uint4 u0, u1;
            u0.x = pack_bf16(pv[0][0], pv[0][1]); u0.y = pack_bf16(pv[0][2], pv[0][3]);
            u0.z = pack_bf16(pv[1][0], pv[1][1]); u0.w = pack_bf16(pv[1][2], pv[1][3]);
            u1.x = pack_bf16(pv[2][0], pv[2][1]); u1.y = pack_bf16(pv[2][2], pv[2][3]);
            u1.z = pack_bf16(pv[3][0], pv[3][1]); u1.w = pack_bf16(pv[3][2], pv[3][3]);
            bf16x8 pa0 = *reinterpret_cast<bf16x8*>(&u0);
            bf16x8 pa1 = *reinterpret_cast<bf16x8*>(&u1);
            dacc[qf] = mfma16(pa0, ones, dacc[qf]);
            dacc[qf] = mfma16(pa1, ones, dacc[qf]);
            #pragma unroll
            for (int kk = 0; kk < 2; ++kk) {
                const bf16x8 pa = kk ? pa1 : pa0;
                const int swzk = ((kk * 4 + lg) ^ (lr & 7)) << 3;
                #pragma unroll
                for (int n = 0; n < 4; ++n) {
                    const int row = n * 16 + lr;
                    bf16x8 vbf = *reinterpret_cast<const bf16x8*>(&Vts[cur][row * 64 + swzk]);
                    o[qf][n] = mfma16(pa, vbf, o[qf][n]);
                }
            }
        }
    }
    #pragma unroll
    for (int qf = 0; qf < 2; ++qf) {
        const int qrow = qt * 128 + w * 32 + qf * 16 + lg * 4;
        #pragma unroll
        for (int r = 0; r < 4; ++r) {
            const float inv = 1.0f / dacc[qf][r];
            #pragma unroll
            for (int n = 0; n < 4; ++n) {
                outp[(long)(b * 1024 + qrow + r) * 768 + h * 64 + n * 16 + lr] =
                    f32_to_bf16(o[qf][n][r] * inv);
            }
        }
    }
}

extern "C" void kernel_launch(void* const* d_in, const int* in_sizes, int n_in,
                              void* d_out, int out_size, void* d_ws, size_t ws_size,
                              hipStream_t stream) {
    (void)in_sizes; (void)n_in; (void)out_size; (void)ws_size;
    const float* x    = (const float*)d_in[0];
    const float* Wqkv = (const float*)d_in[1];
    const float* bqkv = (const float*)d_in[2];
    const float* Wout = (const float*)d_in[3];
    const float* bout = (const float*)d_in[4];

    u16* xb   = (u16*)d_ws;          // 8192*768
    u16* Wqb  = xb  + 6291456;       // 2304*768
    u16* Wob  = Wqb + 1769472;       // 768*768
    u16* qkv  = Wob + 589824;        // 8192*2304 (V slice unused/unwritten)
    u16* vtb  = qkv + 18874368;      // 96*64*1024
    u16* attn = vtb + 6291456;       // 8192*768

    const float sc2 = 0.052058773f;  // 768^-0.5 * log2(e)

    cvt3_k<<<8448, 256, 0, stream>>>(x, Wqkv, Wout, xb);

    gemm_bt_k<0><<<1152, 256, 0, stream>>>(xb, Wqb, bqkv, qkv, vtb, 8192, 2304, 768, 18, 768, sc2);
    attn_k<<<768, 256, 0, stream>>>(qkv, vtb, attn);
    gemm_bt_k<1><<<384, 256, 0, stream>>>(attn, Wob, bout, d_out, nullptr, 8192, 768, 768, 6, 0, 1.0f);
}

// Round 18
// 102.808 us; speedup vs baseline: 1.6137x; 1.0879x over previous
//
#include <hip/hip_runtime.h>
#include <stdint.h>

typedef __bf16 bf16x8 __attribute__((ext_vector_type(8)));
typedef float  f32x4  __attribute__((ext_vector_type(4)));
typedef unsigned short u16;

#define AS1 __attribute__((address_space(1)))
#define AS3 __attribute__((address_space(3)))
#define G2L(gp, lp) __builtin_amdgcn_global_load_lds( \
    (const AS1 unsigned int*)(uintptr_t)(gp), \
    (AS3 unsigned int*)(uintptr_t)(lp), 16, 0, 0)

static __device__ __forceinline__ u16 f32_to_bf16(float f) {
    unsigned u = __float_as_uint(f);
    u += 0x7fffu + ((u >> 16) & 1u);
    return (u16)(u >> 16);
}

// bf16 pair pack: lo -> bits[15:0], hi -> bits[31:16]
static __device__ __forceinline__ unsigned pack_bf16(float lo, float hi) {
    return (unsigned)f32_to_bf16(lo) | ((unsigned)f32_to_bf16(hi) << 16);
}

static __device__ __forceinline__ float fast_exp2(float x) {
    return __builtin_amdgcn_exp2f(x);
}

static __device__ __forceinline__ f32x4 mfma16(bf16x8 a, bf16x8 b, f32x4 c) {
    return __builtin_amdgcn_mfma_f32_16x16x32_bf16(a, b, c, 0, 0, 0);
}

// ---------------- fused fp32 -> bf16 convert for x, W_qkv, W_out ----------------
__global__ void cvt3_k(const float* __restrict__ a, const float* __restrict__ b,
                       const float* __restrict__ c, u16* __restrict__ out) {
    const int i = blockIdx.x * blockDim.x + threadIdx.x;   // vec4 index
    const float* src; int off;
    if (i < 1572864)      { src = a; off = 0; }
    else if (i < 2015232) { src = b; off = 1572864; }
    else                  { src = c; off = 2015232; }
    const float4 v = reinterpret_cast<const float4*>(src)[i - off];
    reinterpret_cast<uint2*>(out)[i] = make_uint2(pack_bf16(v.x, v.y), pack_bf16(v.z, v.w));
}

// ---------------- bf16 GEMM: C[M,N] = A[M,K] @ B[N,K]^T + bias ----------------
// 128x128 tile, BK=64, 2-phase prefetch, dbuf LDS, XCD swizzle.
// Columns gc < qcols get scaled by qsc (pre-folds softmax scale into Q).
template<int OUTF32>
__global__ __launch_bounds__(256, 2) void gemm_bt_k(const u16* __restrict__ A, const u16* __restrict__ B,
                                                    const float* __restrict__ bias, void* __restrict__ Cp,
                                                    int M, int N, int K, int nbx, int qcols, float qsc) {
    __shared__ __align__(16) u16 As[2][128 * 64];
    __shared__ __align__(16) u16 Bs[2][128 * 64];
    const int id = blockIdx.x;
    const int cpx = gridDim.x >> 3;
    const int swz = (id & 7) * cpx + (id >> 3);
    const int bx = swz % nbx, by = swz / nbx;
    const int t = threadIdx.x, w = t >> 6, l = t & 63, lr = l & 15, lg = l >> 4;
    const int wr = w >> 1, wc = w & 1;
    const long rowBase = (long)by * 128;
    const long colBase = (long)bx * 128;

    const f32x4 z = {0.f, 0.f, 0.f, 0.f};
    f32x4 acc[4][4];
    #pragma unroll
    for (int m = 0; m < 4; ++m)
        #pragma unroll
        for (int n = 0; n < 4; ++n) acc[m][n] = z;

    const int kSteps = K >> 6;
    #pragma unroll
    for (int i = 0; i < 4; ++i) {
        const int c = i * 256 + t, row = c >> 3, ch = c & 7;
        const int sch = ch ^ (row & 7);
        G2L(A + (rowBase + row) * K + sch * 8, &As[0][(i * 256 + w * 64) * 8]);
        G2L(B + (colBase + row) * K + sch * 8, &Bs[0][(i * 256 + w * 64) * 8]);
    }
    for (int kt = 0; kt < kSteps; ++kt) {
        const int cur = kt & 1;
        asm volatile("s_waitcnt vmcnt(0)" ::: "memory");
        __builtin_amdgcn_sched_barrier(0);
        __builtin_amdgcn_s_barrier();
        __builtin_amdgcn_sched_barrier(0);
        if (kt + 1 < kSteps) {
            const int k0 = (kt + 1) << 6;
            #pragma unroll
            for (int i = 0; i < 4; ++i) {
                const int c = i * 256 + t, row = c >> 3, ch = c & 7;
                const int sch = ch ^ (row & 7);
                G2L(A + (rowBase + row) * K + k0 + sch * 8, &As[cur ^ 1][(i * 256 + w * 64) * 8]);
                G2L(B + (colBase + row) * K + k0 + sch * 8, &Bs[cur ^ 1][(i * 256 + w * 64) * 8]);
            }
        }
        __builtin_amdgcn_sched_barrier(0);
        #pragma unroll
        for (int kk = 0; kk < 2; ++kk) {
            bf16x8 af[4], bfr[4];
            #pragma unroll
            for (int m = 0; m < 4; ++m) {
                const int row = wr * 64 + m * 16 + lr;
                af[m] = *reinterpret_cast<const bf16x8*>(&As[cur][row * 64 + (((kk * 4 + lg) ^ (lr & 7)) << 3)]);
            }
            #pragma unroll
            for (int n = 0; n < 4; ++n) {
                const int row = wc * 64 + n * 16 + lr;
                bfr[n] = *reinterpret_cast<const bf16x8*>(&Bs[cur][row * 64 + (((kk * 4 + lg) ^ (lr & 7)) << 3)]);
            }
            #pragma unroll
            for (int m = 0; m < 4; ++m)
                #pragma unroll
                for (int n = 0; n < 4; ++n) acc[m][n] = mfma16(af[m], bfr[n], acc[m][n]);
        }
    }
    #pragma unroll
    for (int n = 0; n < 4; ++n) {
        const long gc = colBase + wc * 64 + n * 16 + lr;
        const float bv = bias[gc];
        const float csc = (gc < qcols) ? qsc : 1.0f;
        #pragma unroll
        for (int m = 0; m < 4; ++m) {
            const long gr = rowBase + wr * 64 + m * 16 + lg * 4;
            #pragma unroll
            for (int r = 0; r < 4; ++r) {
                const float v = (acc[m][n][r] + bv) * csc;
                if (OUTF32) reinterpret_cast<float*>(Cp)[(gr + r) * N + gc] = v;
                else        reinterpret_cast<u16*>(Cp)[(gr + r) * N + gc] = f32_to_bf16(v);
            }
        }
    }
}

// ---------------- V transpose with PV k-permutation pi' ----------------
// vt[bh][d][pos p] = V[key = (p>>5)*32 + ((p>>2)&1)*16 + ((p>>3)&3)*4 + (p&3)][d]
__global__ __launch_bounds__(256) void transpose_v_k(const u16* __restrict__ qkv, u16* __restrict__ vt) {
    const int bh = blockIdx.y, b = bh / 12, h = bh % 12;
    const int nt = blockIdx.x;
    __shared__ __align__(16) u16 Ts[64][72];   // [key][d]
    const int t = threadIdx.x;
    const int rr = t >> 2;
    #pragma unroll
    for (int i = 0; i < 2; ++i) {
        const int ch = (t & 3) + i * 4;
        const u16* src = qkv + (long)(b * 1024 + nt * 64 + rr) * 2304 + 1536 + h * 64 + ch * 8;
        *reinterpret_cast<uint4*>(&Ts[rr][ch * 8]) = *reinterpret_cast<const uint4*>(src);
    }
    __syncthreads();
    #pragma unroll
    for (int i = 0; i < 2; ++i) {
        const int ch = (t & 3) + i * 4;   // pos p = ch*8+j
        u16 vals[8];
        #pragma unroll
        for (int j = 0; j < 8; ++j)
            vals[j] = Ts[(ch >> 2) * 32 + (j >> 2) * 16 + (ch & 3) * 4 + (j & 3)][rr];
        u16* dst = vt + (long)(bh * 64 + rr) * 1024 + nt * 64 + ch * 8;
        *reinterpret_cast<uint4*>(dst) = *reinterpret_cast<const uint4*>(vals);
    }
}

// ---------------- flash attention v7: swapped-QK, in-register P, QBLK=128 ----------------
// s = mfma(K, Q): lane holds P[q=qf*16+lr] -> P packs feed PV A-operand directly
// (no P LDS round-trip). Denominator via ones-MFMA (dacc matches o's row layout).
// K/V LDS-staged with G2L dbuf; Q pre-scaled by 768^-0.5*log2e in gemm1 epilogue.
__global__ __launch_bounds__(256, 3) void attn_k(const u16* __restrict__ qkv, const u16* __restrict__ vt,
                                                 u16* __restrict__ outp) {
    const int id = blockIdx.x;
    const int bh = id % 96, qt = id / 96;   // qt in 0..7; same-bh -> same XCD
    const int b = bh / 12, h = bh % 12;
    const int t = threadIdx.x, w = t >> 6, l = t & 63, lr = l & 15, lg = l >> 4;
    __shared__ __align__(16) u16 Ks[2][64 * 64];
    __shared__ __align__(16) u16 Vts[2][64 * 64];   // [d][perm key]

    const u16* kb = qkv + 768 + h * 64;
    const u16* vb = vt + (long)bh * 64 * 1024;

    // stage K/V tile 0
    #pragma unroll
    for (int i = 0; i < 2; ++i) {
        const int c = (i * 4 + w) * 64 + l;
        const int row = c >> 3, sch = (c & 7) ^ (row & 7);
        G2L(kb + (long)(b * 1024 + row) * 2304 + sch * 8, &Ks[0][(i * 4 + w) * 512]);
        G2L(vb + (long)row * 1024 + sch * 8, &Vts[0][(i * 4 + w) * 512]);
    }
    // Q (pre-scaled in gemm1) straight into regs: B-operand rows q = w*32+qf*16+lr
    const u16* qb = qkv + (long)(b * 1024 + qt * 128 + w * 32) * 2304 + h * 64;
    bf16x8 aq[2][2];
    #pragma unroll
    for (int qf = 0; qf < 2; ++qf)
        #pragma unroll
        for (int kk = 0; kk < 2; ++kk)
            aq[qf][kk] = *reinterpret_cast<const bf16x8*>(qb + (long)(qf * 16 + lr) * 2304 + (kk * 4 + lg) * 8);

    const f32x4 z = {0.f, 0.f, 0.f, 0.f};
    f32x4 o[2][4];      // [qf][n]: O[q=qf*16+lg*4+r][d=n*16+lr]
    f32x4 dacc[2];      // [qf]: denom[q=qf*16+lg*4+r]
    #pragma unroll
    for (int qf = 0; qf < 2; ++qf) {
        #pragma unroll
        for (int n = 0; n < 4; ++n) o[qf][n] = z;
        dacc[qf] = z;
    }
    const unsigned one2 = 0x3F803F80u;
    uint4 onesu = make_uint4(one2, one2, one2, one2);
    const bf16x8 ones = *reinterpret_cast<const bf16x8*>(&onesu);

    #pragma unroll 2
    for (int kt = 0; kt < 16; ++kt) {
        const int cur = kt & 1;
        asm volatile("s_waitcnt vmcnt(0)" ::: "memory");
        __builtin_amdgcn_sched_barrier(0);
        __builtin_amdgcn_s_barrier();
        __builtin_amdgcn_sched_barrier(0);
        if (kt < 15) {
            const int ktn = kt + 1;
            #pragma unroll
            for (int i = 0; i < 2; ++i) {
                const int c = (i * 4 + w) * 64 + l;
                const int row = c >> 3, sch = (c & 7) ^ (row & 7);
                G2L(kb + (long)(b * 1024 + ktn * 64 + row) * 2304 + sch * 8, &Ks[cur ^ 1][(i * 4 + w) * 512]);
                G2L(vb + (long)row * 1024 + ktn * 64 + sch * 8, &Vts[cur ^ 1][(i * 4 + w) * 512]);
            }
        }
        __builtin_amdgcn_sched_barrier(0);
        // S^T = K @ Q^T: s[kc][qf] = S[key=kc*16+lg*4+r][q=qf*16+lr]
        f32x4 s[4][2];
        #pragma unroll
        for (int kc = 0; kc < 4; ++kc)
            #pragma unroll
            for (int qf = 0; qf < 2; ++qf) s[kc][qf] = z;
        #pragma unroll
        for (int kk = 0; kk < 2; ++kk) {
            #pragma unroll
            for (int kc = 0; kc < 4; ++kc) {
                const int row = kc * 16 + lr;
                bf16x8 bk = *reinterpret_cast<const bf16x8*>(&Ks[cur][row * 64 + (((kk * 4 + lg) ^ (lr & 7)) << 3)]);
                s[kc][0] = mfma16(bk, aq[0][kk], s[kc][0]);
                s[kc][1] = mfma16(bk, aq[1][kk], s[kc][1]);
            }
        }
        // softmax-lite in-register: p = exp2(s) (Q pre-scaled), pack to PV A-operand
        #pragma unroll
        for (int qf = 0; qf < 2; ++qf) {
            float pv[4][4];
            #pragma unroll
            for (int kc = 0; kc < 4; ++kc)
                #pragma unroll
                for (int r = 0; r < 4; ++r)
                    pv[kc][r] = fast_exp2(s[kc][qf][r]);
            uint4 u0, u1;
            u0.x = pack_bf16(pv[0][0], pv[0][1]); u0.y = pack_bf16(pv[0][2], pv[0][3]);
            u0.z = pack_bf16(pv[1][0], pv[1][1]); u0.w = pack_bf16(pv[1][2], pv[1][3]);
            u1.x = pack_bf16(pv[2][0], pv[2][1]); u1.y = pack_bf16(pv[2][2], pv[2][3]);
            u1.z = pack_bf16(pv[3][0], pv[3][1]); u1.w = pack_bf16(pv[3][2], pv[3][3]);
            bf16x8 pa0 = *reinterpret_cast<bf16x8*>(&u0);
            bf16x8 pa1 = *reinterpret_cast<bf16x8*>(&u1);
            dacc[qf] = mfma16(pa0, ones, dacc[qf]);
            dacc[qf] = mfma16(pa1, ones, dacc[qf]);
            #pragma unroll
            for (int kk = 0; kk < 2; ++kk) {
                const bf16x8 pa = kk ? pa1 : pa0;
                const int swzk = ((kk * 4 + lg) ^ (lr & 7)) << 3;
                #pragma unroll
                for (int n = 0; n < 4; ++n) {
                    const int row = n * 16 + lr;
                    bf16x8 vbf = *reinterpret_cast<const bf16x8*>(&Vts[cur][row * 64 + swzk]);
                    o[qf][n] = mfma16(pa, vbf, o[qf][n]);
                }
            }
        }
    }
    // epilogue: divide by denom, store
    #pragma unroll
    for (int qf = 0; qf < 2; ++qf) {
        const int qrow = qt * 128 + w * 32 + qf * 16 + lg * 4;
        #pragma unroll
        for (int r = 0; r < 4; ++r) {
            const float inv = 1.0f / dacc[qf][r];
            #pragma unroll
            for (int n = 0; n < 4; ++n) {
                outp[(long)(b * 1024 + qrow + r) * 768 + h * 64 + n * 16 + lr] =
                    f32_to_bf16(o[qf][n][r] * inv);
            }
        }
    }
}

extern "C" void kernel_launch(void* const* d_in, const int* in_sizes, int n_in,
                              void* d_out, int out_size, void* d_ws, size_t ws_size,
                              hipStream_t stream) {
    (void)in_sizes; (void)n_in; (void)out_size; (void)ws_size;
    const float* x    = (const float*)d_in[0];
    const float* Wqkv = (const float*)d_in[1];
    const float* bqkv = (const float*)d_in[2];
    const float* Wout = (const float*)d_in[3];
    const float* bout = (const float*)d_in[4];

    u16* xb   = (u16*)d_ws;          // 8192*768
    u16* Wqb  = xb  + 6291456;       // 2304*768
    u16* Wob  = Wqb + 1769472;       // 768*768
    u16* qkv  = Wob + 589824;        // 8192*2304
    u16* vtb  = qkv + 18874368;      // 96*64*1024
    u16* attn = vtb + 6291456;       // 8192*768

    const float sc2 = 0.052058773f;  // 768^-0.5 * log2(e)

    cvt3_k<<<8448, 256, 0, stream>>>(x, Wqkv, Wout, xb);

    gemm_bt_k<0><<<1152, 256, 0, stream>>>(xb, Wqb, bqkv, qkv, 8192, 2304, 768, 18, 768, sc2);
    transpose_v_k<<<dim3(16, 96), 256, 0, stream>>>(qkv, vtb);
    attn_k<<<768, 256, 0, stream>>>(qkv, vtb, attn);
    gemm_bt_k<1><<<384, 256, 0, stream>>>(attn, Wob, bout, d_out, 8192, 768, 768, 6, 0, 1.0f);
}